// Round 4
// baseline (734.075 us; speedup 1.0000x reference)
//
#include <hip/hip_runtime.h>
#include <hip/hip_bf16.h>
#include <math.h>

#define B_    4
#define C_    128
#define H_    96
#define W_    96
#define HW_   9216          // H*W
#define NPIX  36864         // B*HW
#define BHWC  4718592       // B*HW*C
#define BATCH_STRIDE 1179648 // HW*C

typedef __attribute__((ext_vector_type(8))) short bfrag8;
typedef __attribute__((ext_vector_type(4))) float f32x4;

static __device__ __forceinline__ short f2bf(float f) {
  __hip_bfloat16 h = __float2bfloat16(f);
  short s;
  __builtin_memcpy(&s, &h, 2);
  return s;
}

// ---------------- weight transposes ----------------
// wtb: bf16 A-fragment order [k][mt(8)][kk(4)][lane(64)][j(8)]  (147456)
//      element: oc = mt*16 + (lane&15), c = kk*32 + (lane>>4)*8 + j, tap k
// wo:  [k][c4][oc][4]  from off_w [oc][c][k]  (9*32*18*4 = 20736)
// pwt: [c][oc]         from pw_w [oc][c]      (16384)
__global__ void k_transpose_w(const float* __restrict__ de_w,
                              const float* __restrict__ off_w,
                              const float* __restrict__ pw_w,
                              short* __restrict__ wtb, float* __restrict__ wo,
                              float* __restrict__ pwt) {
  int i = blockIdx.x * 256 + threadIdx.x;
  if (i < 147456) {
    int j  = i & 7;
    int l  = (i >> 3) & 63;
    int kk = (i >> 9) & 3;
    int mt = (i >> 11) & 7;
    int k  = i >> 14;
    int oc = mt * 16 + (l & 15);
    int c  = kk * 32 + ((l >> 4) << 3) + j;
    wtb[i] = f2bf(de_w[(oc * 128 + c) * 9 + k]);
  }
  if (i < 20736) {
    int j  = i & 3;
    int oc = (i >> 2) % 18;
    int c4 = (i / 72) % 32;
    int k  = i / 2304;
    wo[i] = off_w[(oc * 128 + c4 * 4 + j) * 9 + k];
  }
  if (i < 16384) {
    int oc = i & 127; int c = i >> 7;
    pwt[i] = pw_w[oc * 128 + c];
  }
}

// ---------------- depthwise 3x3 + bias : NCHW in -> NCHW out ----------------
__global__ void k_dw(const float* __restrict__ x, const float* __restrict__ dw_w,
                     const float* __restrict__ dw_b, float* __restrict__ h1) {
  int i = blockIdx.x * 256 + threadIdx.x;   // NCHW order, coalesced in AND out
  if (i >= BHWC) return;
  int xx = i % 96; int yy = (i / 96) % 96; int c = (i / HW_) % 128; int b = i / BATCH_STRIDE;
  const float* xp = x + (b * 128 + c) * HW_;
  const float* wp = dw_w + c * 9;
  float acc = dw_b[c];
  #pragma unroll
  for (int dy = 0; dy < 3; ++dy) {
    int sy = yy + dy - 1;
    if (sy < 0 || sy >= 96) continue;
    #pragma unroll
    for (int dx = 0; dx < 3; ++dx) {
      int sx = xx + dx - 1;
      if (sx < 0 || sx >= 96) continue;
      acc += xp[sy * 96 + sx] * wp[dy * 3 + dx];
    }
  }
  h1[i] = acc;
}

// ---------------- pointwise 1x1 + bias : NCHW in -> BHWC out ----------------
// tiled GEMM: block = 32 pixels x 128 oc, thread = 4 oc x 4 pix.
__global__ __launch_bounds__(256) void k_pw(
    const float* __restrict__ h1, const float* __restrict__ pwt,
    const float* __restrict__ pw_b, float* __restrict__ s) {
  __shared__ float samp[32 * 128];   // [p4][c][4], 16 KB
  int tid = threadIdx.x;
  int pixbase = blockIdx.x * 32;
  int b = pixbase / HW_;
  int hw0 = pixbase % HW_;

  // stage: thread (=c row) copies 32 contiguous pixels from NCHW h1
  if (tid < 128) {
    const float* hp = h1 + (size_t)(b * 128 + tid) * HW_ + hw0;
    #pragma unroll
    for (int p4 = 0; p4 < 8; ++p4) {
      float4 v = *(const float4*)(hp + p4 * 4);
      *(float4*)&samp[p4 * 512 + tid * 4] = v;   // lane-contiguous 16B: no conflicts
    }
  }
  __syncthreads();

  int to = tid & 31;    // oc = 4*to
  int tp = tid >> 5;    // pixel group p4 = tp
  float acc[4][4];
  #pragma unroll
  for (int i = 0; i < 4; ++i)
    #pragma unroll
    for (int j = 0; j < 4; ++j) acc[i][j] = 0.f;

  const float4* wp4 = (const float4*)pwt;
  const float4* sp4 = (const float4*)&samp[tp * 512];
  #pragma unroll 8
  for (int c = 0; c < 128; ++c) {
    float4 w4 = wp4[c * 32 + to];   // coalesced 512B across 32 lanes, L1-hot
    float4 s4 = sp4[c];             // broadcast, conflict-free
    float wr[4] = {w4.x, w4.y, w4.z, w4.w};
    float sr[4] = {s4.x, s4.y, s4.z, s4.w};
    #pragma unroll
    for (int i = 0; i < 4; ++i)
      #pragma unroll
      for (int j = 0; j < 4; ++j)
        acc[i][j] = fmaf(wr[i], sr[j], acc[i][j]);
  }

  float b0 = pw_b[4 * to + 0], b1 = pw_b[4 * to + 1],
        b2 = pw_b[4 * to + 2], b3 = pw_b[4 * to + 3];
  #pragma unroll
  for (int j = 0; j < 4; ++j) {
    int pix = pixbase + 4 * tp + j;
    float4 v = make_float4(acc[0][j] + b0, acc[1][j] + b1, acc[2][j] + b2, acc[3][j] + b3);
    *(float4*)(s + (size_t)pix * 128 + 4 * to) = v;
  }
}

// ---------------- InstanceNorm stats (per b,c over HW) ----------------
__global__ void k_instats(const float* __restrict__ s, float* __restrict__ ist) {
  int b = blockIdx.x / 36; int tile = blockIdx.x % 36;
  int c = threadIdx.x & 127; int half = threadIdx.x >> 7;
  const float* base = s + (size_t)(b * HW_ + tile * 256) * 128;
  float sum = 0.f, sq = 0.f;
  for (int p = half; p < 256; p += 2) {
    float v = base[p * 128 + c];
    sum += v; sq += v * v;
  }
  __shared__ float r1[256], r2[256];
  r1[threadIdx.x] = sum; r2[threadIdx.x] = sq;
  __syncthreads();
  if (half == 0) {
    atomicAdd(&ist[(b * 128 + c) * 2],     r1[c] + r1[c + 128]);
    atomicAdd(&ist[(b * 128 + c) * 2 + 1], r2[c] + r2[c + 128]);
  }
}

__global__ void k_infin(const float* __restrict__ ist, float* __restrict__ ifin) {
  int i = blockIdx.x * 256 + threadIdx.x;
  if (i >= 512) return;
  float mean = ist[2 * i] * (1.f / 9216.f);
  float var  = ist[2 * i + 1] * (1.f / 9216.f) - mean * mean;
  ifin[2 * i] = mean;
  ifin[2 * i + 1] = rsqrtf(var + 1e-5f);
}

// ---------------- apply IN + ReLU in place ----------------
__global__ void k_inapply(float* __restrict__ s, const float* __restrict__ ifin) {
  int i = blockIdx.x * 256 + threadIdx.x;
  if (i >= BHWC) return;
  int c = i & 127; int b = i / BATCH_STRIDE;
  float m = ifin[(b * 128 + c) * 2], r = ifin[(b * 128 + c) * 2 + 1];
  float v = (s[i] - m) * r;
  s[i] = v > 0.f ? v : 0.f;
}

// ---------------- offset conv 3x3 (128 -> 18) + bias ----------------
__global__ __launch_bounds__(256) void k_off(
    const float* __restrict__ s, const float* __restrict__ wo,
    const float* __restrict__ off_b, float* __restrict__ off) {
  int pix = blockIdx.x * 256 + threadIdx.x;
  int b = pix / HW_; int hw = pix % HW_; int y = hw / 96; int x = hw % 96;
  const float* sb = s + (size_t)b * BATCH_STRIDE;

  float acc[18];
  #pragma unroll
  for (int oc = 0; oc < 18; ++oc) acc[oc] = off_b[oc];

  for (int k = 0; k < 9; ++k) {
    int sy = y + k / 3 - 1;
    int sx = x + k % 3 - 1;
    if (sy < 0 || sy >= 96 || sx < 0 || sx >= 96) continue;
    const float4* win = (const float4*)(sb + (sy * 96 + sx) * 128);
    const float4* wk  = (const float4*)(wo + k * 2304);
    #pragma unroll 2
    for (int c4 = 0; c4 < 32; ++c4) {
      float4 a = win[c4];
      #pragma unroll
      for (int oc = 0; oc < 18; ++oc) {
        float4 w = wk[c4 * 18 + oc];
        acc[oc] = fmaf(a.x, w.x, acc[oc]);
        acc[oc] = fmaf(a.y, w.y, acc[oc]);
        acc[oc] = fmaf(a.z, w.z, acc[oc]);
        acc[oc] = fmaf(a.w, w.w, acc[oc]);
      }
    }
  }
  float* op = off + (size_t)pix * 18;
  #pragma unroll
  for (int oc = 0; oc < 18; ++oc) op[oc] = acc[oc];
}

// ---------------- deformable conv: bf16 MFMA, register-direct B frags ----------------
// wave = 32 oc x 32 pix (2x2 tiles of 16x16, K=1152 over 9 taps x 4 slices of 32).
// block = 4 waves = 128 pixels; grid (NPIX/128, 128/32). No LDS, no syncthreads.
// B-frag: lane l holds pixel (l&15), channels (l>>4)*8+i  == MFMA B layout.
// A-frag: wtb pre-packed so lane-contiguous 16B loads give the fragment.
__global__ __launch_bounds__(256) void k_deform(
    const float* __restrict__ s, const float* __restrict__ off,
    const short* __restrict__ wtb, const float* __restrict__ de_b,
    float* __restrict__ d) {
  int tid = threadIdx.x;
  int lane = tid & 63;
  int wv = tid >> 6;
  int pixbase = blockIdx.x * 128 + wv * 32;
  int mtg0 = blockIdx.y * 2;          // global m-tile (16-oc) index of mt=0

  int lp = lane & 15;
  int g  = lane >> 4;                 // channel group: c base = g*8
  int b_img = pixbase / HW_;
  const float* sb = s + (size_t)b_img * BATCH_STRIDE;

  f32x4 acc00 = {0.f,0.f,0.f,0.f}, acc01 = acc00, acc10 = acc00, acc11 = acc00;

  int pix[2]; int ys[2], xs[2];
  #pragma unroll
  for (int nt = 0; nt < 2; ++nt) {
    pix[nt] = pixbase + nt * 16 + lp;
    int hw = pix[nt] % HW_;
    ys[nt] = hw / 96; xs[nt] = hw % 96;
  }

  const bfrag8* wtb8 = (const bfrag8*)wtb;

  for (int k = 0; k < 9; ++k) {
    // per-(pixel,tap) corner offsets (into sb, float units) + bilinear weights
    int o00[2], o01[2], o10[2], o11[2];
    float f00[2], f01[2], f10[2], f11[2];
    #pragma unroll
    for (int nt = 0; nt < 2; ++nt) {
      float dy = off[pix[nt] * 18 + 2 * k];
      float dx = off[pix[nt] * 18 + 2 * k + 1];
      float py = (float)ys[nt] + (float)(k / 3 - 1) + dy;
      float px = (float)xs[nt] + (float)(k % 3 - 1) + dx;
      float y0f = floorf(py), x0f = floorf(px);
      float ly = py - y0f, lx = px - x0f;
      int y0 = (int)y0f, x0 = (int)x0f;
      bool vy0 = (y0 >= 0) && (y0 < 96), vy1 = (y0 + 1 >= 0) && (y0 + 1 < 96);
      bool vx0 = (x0 >= 0) && (x0 < 96), vx1 = (x0 + 1 >= 0) && (x0 + 1 < 96);
      f00[nt] = (vy0 && vx0) ? (1.f - ly) * (1.f - lx) : 0.f;
      f01[nt] = (vy0 && vx1) ? (1.f - ly) * lx : 0.f;
      f10[nt] = (vy1 && vx0) ? ly * (1.f - lx) : 0.f;
      f11[nt] = (vy1 && vx1) ? ly * lx : 0.f;
      int yc0 = min(max(y0, 0), 95), yc1 = min(max(y0 + 1, 0), 95);
      int xc0 = min(max(x0, 0), 95), xc1 = min(max(x0 + 1, 0), 95);
      int cb = g * 8;
      o00[nt] = (yc0 * 96 + xc0) * 128 + cb;
      o01[nt] = (yc0 * 96 + xc1) * 128 + cb;
      o10[nt] = (yc1 * 96 + xc0) * 128 + cb;
      o11[nt] = (yc1 * 96 + xc1) * 128 + cb;
    }
    #pragma unroll
    for (int kk = 0; kk < 4; ++kk) {
      int co = kk * 32;
      bfrag8 bf[2];
      #pragma unroll
      for (int nt = 0; nt < 2; ++nt) {
        float4 a0 = *(const float4*)(sb + o00[nt] + co);
        float4 a1 = *(const float4*)(sb + o00[nt] + co + 4);
        float4 b0 = *(const float4*)(sb + o01[nt] + co);
        float4 b1 = *(const float4*)(sb + o01[nt] + co + 4);
        float4 c0 = *(const float4*)(sb + o10[nt] + co);
        float4 c1 = *(const float4*)(sb + o10[nt] + co + 4);
        float4 d0 = *(const float4*)(sb + o11[nt] + co);
        float4 d1 = *(const float4*)(sb + o11[nt] + co + 4);
        float w00 = f00[nt], w01 = f01[nt], w10 = f10[nt], w11 = f11[nt];
        bf[nt][0] = f2bf(a0.x * w00 + b0.x * w01 + c0.x * w10 + d0.x * w11);
        bf[nt][1] = f2bf(a0.y * w00 + b0.y * w01 + c0.y * w10 + d0.y * w11);
        bf[nt][2] = f2bf(a0.z * w00 + b0.z * w01 + c0.z * w10 + d0.z * w11);
        bf[nt][3] = f2bf(a0.w * w00 + b0.w * w01 + c0.w * w10 + d0.w * w11);
        bf[nt][4] = f2bf(a1.x * w00 + b1.x * w01 + c1.x * w10 + d1.x * w11);
        bf[nt][5] = f2bf(a1.y * w00 + b1.y * w01 + c1.y * w10 + d1.y * w11);
        bf[nt][6] = f2bf(a1.z * w00 + b1.z * w01 + c1.z * w10 + d1.z * w11);
        bf[nt][7] = f2bf(a1.w * w00 + b1.w * w01 + c1.w * w10 + d1.w * w11);
      }
      bfrag8 af0 = wtb8[((k * 8 + mtg0 + 0) * 4 + kk) * 64 + lane];
      bfrag8 af1 = wtb8[((k * 8 + mtg0 + 1) * 4 + kk) * 64 + lane];
      acc00 = __builtin_amdgcn_mfma_f32_16x16x32_bf16(af0, bf[0], acc00, 0, 0, 0);
      acc01 = __builtin_amdgcn_mfma_f32_16x16x32_bf16(af0, bf[1], acc01, 0, 0, 0);
      acc10 = __builtin_amdgcn_mfma_f32_16x16x32_bf16(af1, bf[0], acc10, 0, 0, 0);
      acc11 = __builtin_amdgcn_mfma_f32_16x16x32_bf16(af1, bf[1], acc11, 0, 0, 0);
    }
  }

  // epilogue: D lane l, reg r -> oc_local = g*4 + r, pixel = lane&15
  #pragma unroll
  for (int mt = 0; mt < 2; ++mt) {
    int oc = (mtg0 + mt) * 16 + g * 4;
    float4 bias = *(const float4*)(de_b + oc);
    #pragma unroll
    for (int nt = 0; nt < 2; ++nt) {
      f32x4 a = mt == 0 ? (nt == 0 ? acc00 : acc01) : (nt == 0 ? acc10 : acc11);
      float4 v = make_float4(a[0] + bias.x, a[1] + bias.y, a[2] + bias.z, a[3] + bias.w);
      *(float4*)(d + (size_t)pix[nt] * 128 + oc) = v;
    }
  }
}

// ---------------- GroupNorm(1,C) stats per b ----------------
__global__ void k_gnstats(const float* __restrict__ d, float* __restrict__ gst) {
  int b = blockIdx.x / 36; int tile = blockIdx.x % 36;
  const float* base = d + (size_t)b * BATCH_STRIDE + tile * 32768;
  float sum = 0.f, sq = 0.f;
  for (int p = threadIdx.x; p < 32768; p += 256) {
    float v = base[p]; sum += v; sq += v * v;
  }
  __shared__ float r1[256], r2[256];
  r1[threadIdx.x] = sum; r2[threadIdx.x] = sq;
  __syncthreads();
  for (int st = 128; st > 0; st >>= 1) {
    if (threadIdx.x < st) {
      r1[threadIdx.x] += r1[threadIdx.x + st];
      r2[threadIdx.x] += r2[threadIdx.x + st];
    }
    __syncthreads();
  }
  if (threadIdx.x == 0) {
    atomicAdd(&gst[b * 2],     r1[0]);
    atomicAdd(&gst[b * 2 + 1], r2[0]);
  }
}

__global__ void k_gnfin(const float* __restrict__ gst, float* __restrict__ gfin) {
  int b = threadIdx.x;
  if (b >= 4) return;
  const float invN = 1.f / (float)BATCH_STRIDE;
  float mean = gst[2 * b] * invN;
  float var  = gst[2 * b + 1] * invN - mean * mean;
  gfin[2 * b] = mean;
  gfin[2 * b + 1] = rsqrtf(var + 1e-5f);
}

// ---------------- final: GN affine + sigmoid gate, BHWC -> NCHW ----------------
__global__ void k_final(const float* __restrict__ d, const float* __restrict__ s,
                        const float* __restrict__ gfin, const float* __restrict__ gn_w,
                        const float* __restrict__ gn_b, float* __restrict__ out) {
  int i = blockIdx.x * 256 + threadIdx.x;   // NCHW order -> coalesced writes
  if (i >= BHWC) return;
  int xx = i % 96; int yy = (i / 96) % 96; int c = (i / HW_) % 128; int b = i / BATCH_STRIDE;
  size_t cl = (size_t)(b * HW_ + yy * 96 + xx) * 128 + c;
  float dv = d[cl], sv = s[cl];
  float dn = (dv - gfin[2 * b]) * gfin[2 * b + 1] * gn_w[c] + gn_b[c];
  float g = 1.f / (1.f + expf(-dn));
  out[i] = g * sv + sv;
}

extern "C" void kernel_launch(void* const* d_in, const int* in_sizes, int n_in,
                              void* d_out, int out_size, void* d_ws, size_t ws_size,
                              hipStream_t stream) {
  (void)in_sizes; (void)n_in; (void)out_size; (void)ws_size;
  const float* x     = (const float*)d_in[0];
  const float* dw_w  = (const float*)d_in[1];
  const float* dw_b  = (const float*)d_in[2];
  const float* pw_w  = (const float*)d_in[3];
  const float* pw_b  = (const float*)d_in[4];
  const float* off_w = (const float*)d_in[5];
  const float* off_b = (const float*)d_in[6];
  const float* de_w  = (const float*)d_in[7];
  const float* de_b  = (const float*)d_in[8];
  const float* gn_w  = (const float*)d_in[9];
  const float* gn_b  = (const float*)d_in[10];
  float* out = (float*)d_out;

  float* ws   = (float*)d_ws;
  float* h1   = ws;                 // NCHW depthwise out; reused as deform out (BHWC)
  float* s    = h1 + BHWC;          // BHWC shortcut
  float* off  = s + BHWC;           // [NPIX][18]
  short* wtb  = (short*)(off + NPIX * 18);  // bf16 A-frag packed de_w (147456 bf16)
  float* wo   = off + NPIX * 18 + 73728;    // [9][32][18][4]
  float* pwt  = wo + 20736;         // [c][oc] 16384
  float* ist  = pwt + 16384;        // [B][C][2] sum,sumsq
  float* ifin = ist + 1024;         // [B][C][2] mean,rstd
  float* gst  = ifin + 1024;        // [B][2]
  float* gfin = gst + 8;            // [B][2]

  // zero the atomic accumulators (ist..gfin region)
  hipMemsetAsync(ist, 0, (1024 + 1024 + 8 + 8) * sizeof(float), stream);

  k_transpose_w<<<576, 256, 0, stream>>>(de_w, off_w, pw_w, wtb, wo, pwt);
  k_dw<<<BHWC / 256, 256, 0, stream>>>(x, dw_w, dw_b, h1);
  k_pw<<<NPIX / 32, 256, 0, stream>>>(h1, pwt, pw_b, s);
  k_instats<<<4 * 36, 256, 0, stream>>>(s, ist);
  k_infin<<<2, 256, 0, stream>>>(ist, ifin);
  k_inapply<<<BHWC / 256, 256, 0, stream>>>(s, ifin);
  k_off<<<NPIX / 256, 256, 0, stream>>>(s, wo, off_b, off);
  dim3 gd(NPIX / 128, 4);
  k_deform<<<gd, 256, 0, stream>>>(s, off, wtb, de_b, h1);
  k_gnstats<<<4 * 36, 256, 0, stream>>>(h1, gst);
  k_gnfin<<<1, 64, 0, stream>>>(gst, gfin);
  k_final<<<BHWC / 256, 256, 0, stream>>>(h1, s, gfin, gn_w, gn_b, out);
}

// Round 5
// 531.882 us; speedup vs baseline: 1.3801x; 1.3801x over previous
//
#include <hip/hip_runtime.h>
#include <hip/hip_bf16.h>
#include <math.h>

#define B_    4
#define C_    128
#define H_    96
#define W_    96
#define HW_   9216          // H*W
#define NPIX  36864         // B*HW
#define PIX_CHUNK 18432     // NPIX/2
#define BHWC  4718592       // B*HW*C
#define BATCH_STRIDE 1179648 // HW*C

typedef __attribute__((ext_vector_type(8))) short bfrag8;
typedef __attribute__((ext_vector_type(4))) float f32x4;

static __device__ __forceinline__ short f2bf(float f) {
  __hip_bfloat16 h = __float2bfloat16(f);
  short s;
  __builtin_memcpy(&s, &h, 2);
  return s;
}

// ---------------- weight transposes ----------------
// wtb: bf16 A-fragment order [k][mt(8)][kk(4)][lane(64)][j(8)]  (147456)
//      element: oc = mt*16 + (lane&15), c = kk*32 + (lane>>4)*8 + j, tap k
// wo:  [k][c4][oc][4]  from off_w [oc][c][k]  (9*32*18*4 = 20736)
// pwt: [c][oc]         from pw_w [oc][c]      (16384)
__global__ void k_transpose_w(const float* __restrict__ de_w,
                              const float* __restrict__ off_w,
                              const float* __restrict__ pw_w,
                              short* __restrict__ wtb, float* __restrict__ wo,
                              float* __restrict__ pwt) {
  int i = blockIdx.x * 256 + threadIdx.x;
  if (i < 147456) {
    int j  = i & 7;
    int l  = (i >> 3) & 63;
    int kk = (i >> 9) & 3;
    int mt = (i >> 11) & 7;
    int k  = i >> 14;
    int oc = mt * 16 + (l & 15);
    int c  = kk * 32 + ((l >> 4) << 3) + j;
    wtb[i] = f2bf(de_w[(oc * 128 + c) * 9 + k]);
  }
  if (i < 20736) {
    int j  = i & 3;
    int oc = (i >> 2) % 18;
    int c4 = (i / 72) % 32;
    int k  = i / 2304;
    wo[i] = off_w[(oc * 128 + c4 * 4 + j) * 9 + k];
  }
  if (i < 16384) {
    int oc = i & 127; int c = i >> 7;
    pwt[i] = pw_w[oc * 128 + c];
  }
}

// ---------------- depthwise 3x3 + bias : NCHW in -> NCHW out ----------------
__global__ void k_dw(const float* __restrict__ x, const float* __restrict__ dw_w,
                     const float* __restrict__ dw_b, float* __restrict__ h1) {
  int i = blockIdx.x * 256 + threadIdx.x;   // NCHW order, coalesced in AND out
  if (i >= BHWC) return;
  int xx = i % 96; int yy = (i / 96) % 96; int c = (i / HW_) % 128; int b = i / BATCH_STRIDE;
  const float* xp = x + (b * 128 + c) * HW_;
  const float* wp = dw_w + c * 9;
  float acc = dw_b[c];
  #pragma unroll
  for (int dy = 0; dy < 3; ++dy) {
    int sy = yy + dy - 1;
    if (sy < 0 || sy >= 96) continue;
    #pragma unroll
    for (int dx = 0; dx < 3; ++dx) {
      int sx = xx + dx - 1;
      if (sx < 0 || sx >= 96) continue;
      acc += xp[sy * 96 + sx] * wp[dy * 3 + dx];
    }
  }
  h1[i] = acc;
}

// ---------------- pointwise 1x1 + bias : NCHW in -> BHWC out ----------------
// tiled GEMM: block = 32 pixels x 128 oc, thread = 4 oc x 4 pix.
__global__ __launch_bounds__(256) void k_pw(
    const float* __restrict__ h1, const float* __restrict__ pwt,
    const float* __restrict__ pw_b, float* __restrict__ s) {
  __shared__ float samp[32 * 128];   // [p4][c][4], 16 KB
  int tid = threadIdx.x;
  int pixbase = blockIdx.x * 32;
  int b = pixbase / HW_;
  int hw0 = pixbase % HW_;

  // stage: thread (=c row) copies 32 contiguous pixels from NCHW h1
  if (tid < 128) {
    const float* hp = h1 + (size_t)(b * 128 + tid) * HW_ + hw0;
    #pragma unroll
    for (int p4 = 0; p4 < 8; ++p4) {
      float4 v = *(const float4*)(hp + p4 * 4);
      *(float4*)&samp[p4 * 512 + tid * 4] = v;   // lane-contiguous 16B: no conflicts
    }
  }
  __syncthreads();

  int to = tid & 31;    // oc = 4*to
  int tp = tid >> 5;    // pixel group p4 = tp
  float acc[4][4];
  #pragma unroll
  for (int i = 0; i < 4; ++i)
    #pragma unroll
    for (int j = 0; j < 4; ++j) acc[i][j] = 0.f;

  const float4* wp4 = (const float4*)pwt;
  const float4* sp4 = (const float4*)&samp[tp * 512];
  #pragma unroll 8
  for (int c = 0; c < 128; ++c) {
    float4 w4 = wp4[c * 32 + to];   // coalesced 512B across 32 lanes, L1-hot
    float4 s4 = sp4[c];             // broadcast, conflict-free
    float wr[4] = {w4.x, w4.y, w4.z, w4.w};
    float sr[4] = {s4.x, s4.y, s4.z, s4.w};
    #pragma unroll
    for (int i = 0; i < 4; ++i)
      #pragma unroll
      for (int j = 0; j < 4; ++j)
        acc[i][j] = fmaf(wr[i], sr[j], acc[i][j]);
  }

  float b0 = pw_b[4 * to + 0], b1 = pw_b[4 * to + 1],
        b2 = pw_b[4 * to + 2], b3 = pw_b[4 * to + 3];
  #pragma unroll
  for (int j = 0; j < 4; ++j) {
    int pix = pixbase + 4 * tp + j;
    float4 v = make_float4(acc[0][j] + b0, acc[1][j] + b1, acc[2][j] + b2, acc[3][j] + b3);
    *(float4*)(s + (size_t)pix * 128 + 4 * to) = v;
  }
}

// ---------------- InstanceNorm stats (per b,c over HW) ----------------
__global__ void k_instats(const float* __restrict__ s, float* __restrict__ ist) {
  int b = blockIdx.x / 36; int tile = blockIdx.x % 36;
  int c = threadIdx.x & 127; int half = threadIdx.x >> 7;
  const float* base = s + (size_t)(b * HW_ + tile * 256) * 128;
  float sum = 0.f, sq = 0.f;
  for (int p = half; p < 256; p += 2) {
    float v = base[p * 128 + c];
    sum += v; sq += v * v;
  }
  __shared__ float r1[256], r2[256];
  r1[threadIdx.x] = sum; r2[threadIdx.x] = sq;
  __syncthreads();
  if (half == 0) {
    atomicAdd(&ist[(b * 128 + c) * 2],     r1[c] + r1[c + 128]);
    atomicAdd(&ist[(b * 128 + c) * 2 + 1], r2[c] + r2[c + 128]);
  }
}

__global__ void k_infin(const float* __restrict__ ist, float* __restrict__ ifin) {
  int i = blockIdx.x * 256 + threadIdx.x;
  if (i >= 512) return;
  float mean = ist[2 * i] * (1.f / 9216.f);
  float var  = ist[2 * i + 1] * (1.f / 9216.f) - mean * mean;
  ifin[2 * i] = mean;
  ifin[2 * i + 1] = rsqrtf(var + 1e-5f);
}

// ---------------- apply IN + ReLU in place ----------------
__global__ void k_inapply(float* __restrict__ s, const float* __restrict__ ifin) {
  int i = blockIdx.x * 256 + threadIdx.x;
  if (i >= BHWC) return;
  int c = i & 127; int b = i / BATCH_STRIDE;
  float m = ifin[(b * 128 + c) * 2], r = ifin[(b * 128 + c) * 2 + 1];
  float v = (s[i] - m) * r;
  s[i] = v > 0.f ? v : 0.f;
}

// ---------------- offset conv 3x3 (128 -> 18) + bias ----------------
__global__ __launch_bounds__(256) void k_off(
    const float* __restrict__ s, const float* __restrict__ wo,
    const float* __restrict__ off_b, float* __restrict__ off) {
  int pix = blockIdx.x * 256 + threadIdx.x;
  int b = pix / HW_; int hw = pix % HW_; int y = hw / 96; int x = hw % 96;
  const float* sb = s + (size_t)b * BATCH_STRIDE;

  float acc[18];
  #pragma unroll
  for (int oc = 0; oc < 18; ++oc) acc[oc] = off_b[oc];

  for (int k = 0; k < 9; ++k) {
    int sy = y + k / 3 - 1;
    int sx = x + k % 3 - 1;
    if (sy < 0 || sy >= 96 || sx < 0 || sx >= 96) continue;
    const float4* win = (const float4*)(sb + (sy * 96 + sx) * 128);
    const float4* wk  = (const float4*)(wo + k * 2304);
    #pragma unroll 2
    for (int c4 = 0; c4 < 32; ++c4) {
      float4 a = win[c4];
      #pragma unroll
      for (int oc = 0; oc < 18; ++oc) {
        float4 w = wk[c4 * 18 + oc];
        acc[oc] = fmaf(a.x, w.x, acc[oc]);
        acc[oc] = fmaf(a.y, w.y, acc[oc]);
        acc[oc] = fmaf(a.z, w.z, acc[oc]);
        acc[oc] = fmaf(a.w, w.w, acc[oc]);
      }
    }
  }
  float* op = off + (size_t)pix * 18;
  #pragma unroll
  for (int oc = 0; oc < 18; ++oc) op[oc] = acc[oc];
}

// ---------------- deform sampling: bilinear once per (pixel,tap,c), bf16 out ----
// thread = (pixel, tap); grid (PIX_CHUNK/256, 9). Output in MFMA B-frag order:
// samp[pixblk][kslice=k*4+kk][lane=g*16+lp][j]  (bf16), pixel=pixblk*16+lp,
// c = kk*32 + g*8 + j.  Massive occupancy hides gather latency.
__global__ __launch_bounds__(256) void k_sample(
    const float* __restrict__ s, const float* __restrict__ off,
    short* __restrict__ samp, int p0) {
  int k  = blockIdx.y;
  int pl = blockIdx.x * 256 + threadIdx.x;   // local pixel within chunk
  int pix = p0 + pl;
  int b = pix / HW_; int hw = pix % HW_; int y = hw / 96; int x = hw % 96;
  const float* sb = s + (size_t)b * BATCH_STRIDE;

  float dy = off[pix * 18 + 2 * k];
  float dx = off[pix * 18 + 2 * k + 1];
  float py = (float)y + (float)(k / 3 - 1) + dy;
  float px = (float)x + (float)(k % 3 - 1) + dx;
  float y0f = floorf(py), x0f = floorf(px);
  float ly = py - y0f, lx = px - x0f;
  int y0 = (int)y0f, x0 = (int)x0f;
  bool vy0 = (y0 >= 0) && (y0 < 96), vy1 = (y0 + 1 >= 0) && (y0 + 1 < 96);
  bool vx0 = (x0 >= 0) && (x0 < 96), vx1 = (x0 + 1 >= 0) && (x0 + 1 < 96);
  float w00 = (vy0 && vx0) ? (1.f - ly) * (1.f - lx) : 0.f;
  float w01 = (vy0 && vx1) ? (1.f - ly) * lx : 0.f;
  float w10 = (vy1 && vx0) ? ly * (1.f - lx) : 0.f;
  float w11 = (vy1 && vx1) ? ly * lx : 0.f;
  int yc0 = min(max(y0, 0), 95), yc1 = min(max(y0 + 1, 0), 95);
  int xc0 = min(max(x0, 0), 95), xc1 = min(max(x0 + 1, 0), 95);
  const float* p00 = sb + (yc0 * 96 + xc0) * 128;
  const float* p01 = sb + (yc0 * 96 + xc1) * 128;
  const float* p10 = sb + (yc1 * 96 + xc0) * 128;
  const float* p11 = sb + (yc1 * 96 + xc1) * 128;

  int pixblk = pl >> 4, lp = pl & 15;
  bfrag8* sp = (bfrag8*)samp;
  size_t base = ((size_t)pixblk * 36 + k * 4) * 64 + lp;   // + kk*64 + g*16

  #pragma unroll 4
  for (int c8 = 0; c8 < 16; ++c8) {
    int c = c8 * 8;
    float4 a0 = *(const float4*)(p00 + c), a1 = *(const float4*)(p00 + c + 4);
    float4 b0 = *(const float4*)(p01 + c), b1 = *(const float4*)(p01 + c + 4);
    float4 c0 = *(const float4*)(p10 + c), c1 = *(const float4*)(p10 + c + 4);
    float4 d0 = *(const float4*)(p11 + c), d1 = *(const float4*)(p11 + c + 4);
    bfrag8 r;
    r[0] = f2bf(a0.x * w00 + b0.x * w01 + c0.x * w10 + d0.x * w11);
    r[1] = f2bf(a0.y * w00 + b0.y * w01 + c0.y * w10 + d0.y * w11);
    r[2] = f2bf(a0.z * w00 + b0.z * w01 + c0.z * w10 + d0.z * w11);
    r[3] = f2bf(a0.w * w00 + b0.w * w01 + c0.w * w10 + d0.w * w11);
    r[4] = f2bf(a1.x * w00 + b1.x * w01 + c1.x * w10 + d1.x * w11);
    r[5] = f2bf(a1.y * w00 + b1.y * w01 + c1.y * w10 + d1.y * w11);
    r[6] = f2bf(a1.z * w00 + b1.z * w01 + c1.z * w10 + d1.z * w11);
    r[7] = f2bf(a1.w * w00 + b1.w * w01 + c1.w * w10 + d1.w * w11);
    int kk = c8 >> 2, g = c8 & 3;
    sp[base + kk * 64 + g * 16] = r;
  }
}

// ---------------- deform GEMM: D[oc][pix] = sum_K W*samp, bf16 MFMA ----------
// block = 128 oc x 64 pix, 4 waves (2 oc-groups x 2 pix-groups);
// wave = 64 oc (4 mt) x 32 pix (2 pixblk). All frag loads coalesced 1KB blocks.
// Epilogue fuses bias + GroupNorm partial sums (removes k_gnstats).
__global__ __launch_bounds__(256) void k_degemm(
    const short* __restrict__ samp, const short* __restrict__ wtb,
    const float* __restrict__ de_b, float* __restrict__ d,
    float* __restrict__ gst, int p0) {
  int tid = threadIdx.x;
  int lane = tid & 63, wv = tid >> 6;
  int pixblk = blockIdx.x * 4 + (wv & 1) * 2;   // local; covers pixblk, pixblk+1
  int mtg0 = (wv >> 1) * 4;                     // 4 consecutive 16-oc tiles
  const bfrag8* sp = (const bfrag8*)samp;
  const bfrag8* wp = (const bfrag8*)wtb;

  f32x4 acc[4][2];
  #pragma unroll
  for (int m = 0; m < 4; ++m)
    #pragma unroll
    for (int n = 0; n < 2; ++n) acc[m][n] = (f32x4){0.f, 0.f, 0.f, 0.f};

  #pragma unroll 4
  for (int ks = 0; ks < 36; ++ks) {
    bfrag8 bf0 = sp[((size_t)(pixblk + 0) * 36 + ks) * 64 + lane];
    bfrag8 bf1 = sp[((size_t)(pixblk + 1) * 36 + ks) * 64 + lane];
    int k = ks >> 2, kk = ks & 3;
    #pragma unroll
    for (int m = 0; m < 4; ++m) {
      bfrag8 af = wp[((size_t)((k * 8 + mtg0 + m) * 4 + kk)) * 64 + lane];
      acc[m][0] = __builtin_amdgcn_mfma_f32_16x16x32_bf16(af, bf0, acc[m][0], 0, 0, 0);
      acc[m][1] = __builtin_amdgcn_mfma_f32_16x16x32_bf16(af, bf1, acc[m][1], 0, 0, 0);
    }
  }

  // epilogue: bias + store + GN partials. D: lane l reg r -> oc_local=(l>>4)*4+r, pix=l&15
  int g = lane >> 4, lp = lane & 15;
  float lsum = 0.f, lsq = 0.f;
  #pragma unroll
  for (int m = 0; m < 4; ++m) {
    int oc = (mtg0 + m) * 16 + g * 4;
    float4 bias = *(const float4*)(de_b + oc);
    #pragma unroll
    for (int n = 0; n < 2; ++n) {
      int pix = p0 + (pixblk + n) * 16 + lp;
      f32x4 a = acc[m][n];
      float4 v = make_float4(a[0] + bias.x, a[1] + bias.y, a[2] + bias.z, a[3] + bias.w);
      *(float4*)(d + (size_t)pix * 128 + oc) = v;
      lsum += v.x + v.y + v.z + v.w;
      lsq  += v.x * v.x + v.y * v.y + v.z * v.z + v.w * v.w;
    }
  }
  __shared__ float r1[256], r2[256];
  r1[tid] = lsum; r2[tid] = lsq;
  __syncthreads();
  for (int st = 128; st > 0; st >>= 1) {
    if (tid < st) { r1[tid] += r1[tid + st]; r2[tid] += r2[tid + st]; }
    __syncthreads();
  }
  if (tid == 0) {
    int b = (p0 + blockIdx.x * 64) / HW_;
    atomicAdd(&gst[b * 2],     r1[0]);
    atomicAdd(&gst[b * 2 + 1], r2[0]);
  }
}

__global__ void k_gnfin(const float* __restrict__ gst, float* __restrict__ gfin) {
  int b = threadIdx.x;
  if (b >= 4) return;
  const float invN = 1.f / (float)BATCH_STRIDE;
  float mean = gst[2 * b] * invN;
  float var  = gst[2 * b + 1] * invN - mean * mean;
  gfin[2 * b] = mean;
  gfin[2 * b + 1] = rsqrtf(var + 1e-5f);
}

// ---------------- final: GN affine + sigmoid gate, BHWC -> NCHW ----------------
__global__ void k_final(const float* __restrict__ d, const float* __restrict__ s,
                        const float* __restrict__ gfin, const float* __restrict__ gn_w,
                        const float* __restrict__ gn_b, float* __restrict__ out) {
  int i = blockIdx.x * 256 + threadIdx.x;   // NCHW order -> coalesced writes
  if (i >= BHWC) return;
  int xx = i % 96; int yy = (i / 96) % 96; int c = (i / HW_) % 128; int b = i / BATCH_STRIDE;
  size_t cl = (size_t)(b * HW_ + yy * 96 + xx) * 128 + c;
  float dv = d[cl], sv = s[cl];
  float dn = (dv - gfin[2 * b]) * gfin[2 * b + 1] * gn_w[c] + gn_b[c];
  float g = 1.f / (1.f + expf(-dn));
  out[i] = g * sv + sv;
}

extern "C" void kernel_launch(void* const* d_in, const int* in_sizes, int n_in,
                              void* d_out, int out_size, void* d_ws, size_t ws_size,
                              hipStream_t stream) {
  (void)in_sizes; (void)n_in; (void)out_size; (void)ws_size;
  const float* x     = (const float*)d_in[0];
  const float* dw_w  = (const float*)d_in[1];
  const float* dw_b  = (const float*)d_in[2];
  const float* pw_w  = (const float*)d_in[3];
  const float* pw_b  = (const float*)d_in[4];
  const float* off_w = (const float*)d_in[5];
  const float* off_b = (const float*)d_in[6];
  const float* de_w  = (const float*)d_in[7];
  const float* de_b  = (const float*)d_in[8];
  const float* gn_w  = (const float*)d_in[9];
  const float* gn_b  = (const float*)d_in[10];
  float* out = (float*)d_out;

  float* ws   = (float*)d_ws;
  float* h1   = ws;                 // NCHW depthwise out; reused as deform out d (BHWC)
  float* s    = h1 + BHWC;          // BHWC shortcut
  float* off  = s + BHWC;           // [NPIX][18]
  short* wtb  = (short*)(off + NPIX * 18);  // bf16 A-frag packed de_w (147456 bf16)
  float* wo   = off + NPIX * 18 + 73728;    // [9][32][18][4]
  float* pwt  = wo + 20736;         // [c][oc] 16384
  float* ist  = pwt + 16384;        // [B][C][2] sum,sumsq
  float* ifin = ist + 1024;         // [B][C][2] mean,rstd
  float* gst  = ifin + 1024;        // [B][2]
  float* gfin = gst + 8;            // [B][2]
  short* samp = (short*)(gfin + 8); // bf16 B-frag samples, PIX_CHUNK*1152 (42.5 MB)

  // zero the atomic accumulators (ist..gfin region)
  hipMemsetAsync(ist, 0, (1024 + 1024 + 8 + 8) * sizeof(float), stream);

  k_transpose_w<<<576, 256, 0, stream>>>(de_w, off_w, pw_w, wtb, wo, pwt);
  k_dw<<<BHWC / 256, 256, 0, stream>>>(x, dw_w, dw_b, h1);
  k_pw<<<NPIX / 32, 256, 0, stream>>>(h1, pwt, pw_b, s);
  k_instats<<<4 * 36, 256, 0, stream>>>(s, ist);
  k_infin<<<2, 256, 0, stream>>>(ist, ifin);
  k_inapply<<<BHWC / 256, 256, 0, stream>>>(s, ifin);
  k_off<<<NPIX / 256, 256, 0, stream>>>(s, wo, off_b, off);

  dim3 sgrid(PIX_CHUNK / 256, 9);
  for (int chunk = 0; chunk < 2; ++chunk) {
    int p0 = chunk * PIX_CHUNK;
    k_sample<<<sgrid, 256, 0, stream>>>(s, off, samp, p0);
    k_degemm<<<PIX_CHUNK / 64, 256, 0, stream>>>(samp, wtb, de_b, h1, gst, p0);
  }

  k_gnfin<<<1, 64, 0, stream>>>(gst, gfin);
  k_final<<<BHWC / 256, 256, 0, stream>>>(h1, s, gfin, gn_w, gn_b, out);
}

// Round 6
// 393.735 us; speedup vs baseline: 1.8644x; 1.3509x over previous
//
#include <hip/hip_runtime.h>
#include <hip/hip_bf16.h>
#include <math.h>

#define B_    4
#define C_    128
#define H_    96
#define W_    96
#define HW_   9216          // H*W
#define NPIX  36864         // B*HW
#define PIX_CHUNK 18432     // NPIX/2
#define BHWC  4718592       // B*HW*C
#define BATCH_STRIDE 1179648 // HW*C

typedef __attribute__((ext_vector_type(8))) short bfrag8;
typedef __attribute__((ext_vector_type(4))) float f32x4;

static __device__ __forceinline__ short f2bf(float f) {
  __hip_bfloat16 h = __float2bfloat16(f);
  short s;
  __builtin_memcpy(&s, &h, 2);
  return s;
}

// ---------------- weight transposes ----------------
// wtb: bf16 A-fragment order [k][mt(8)][kk(4)][lane(64)][j(8)]  (147456)
//      element: oc = mt*16 + (lane&15), c = kk*32 + (lane>>4)*8 + j, tap k
// wo:  [k][c4][oc][4]  from off_w [oc][c][k]  (9*32*18*4 = 20736)
// pwt: [c][oc]         from pw_w [oc][c]      (16384)
__global__ void k_transpose_w(const float* __restrict__ de_w,
                              const float* __restrict__ off_w,
                              const float* __restrict__ pw_w,
                              short* __restrict__ wtb, float* __restrict__ wo,
                              float* __restrict__ pwt) {
  int i = blockIdx.x * 256 + threadIdx.x;
  if (i < 147456) {
    int j  = i & 7;
    int l  = (i >> 3) & 63;
    int kk = (i >> 9) & 3;
    int mt = (i >> 11) & 7;
    int k  = i >> 14;
    int oc = mt * 16 + (l & 15);
    int c  = kk * 32 + ((l >> 4) << 3) + j;
    wtb[i] = f2bf(de_w[(oc * 128 + c) * 9 + k]);
  }
  if (i < 20736) {
    int j  = i & 3;
    int oc = (i >> 2) % 18;
    int c4 = (i / 72) % 32;
    int k  = i / 2304;
    wo[i] = off_w[(oc * 128 + c4 * 4 + j) * 9 + k];
  }
  if (i < 16384) {
    int oc = i & 127; int c = i >> 7;
    pwt[i] = pw_w[oc * 128 + c];
  }
}

// ---------------- depthwise 3x3 + bias : NCHW in -> NCHW out ----------------
__global__ void k_dw(const float* __restrict__ x, const float* __restrict__ dw_w,
                     const float* __restrict__ dw_b, float* __restrict__ h1) {
  int i = blockIdx.x * 256 + threadIdx.x;   // NCHW order, coalesced in AND out
  if (i >= BHWC) return;
  int xx = i % 96; int yy = (i / 96) % 96; int c = (i / HW_) % 128; int b = i / BATCH_STRIDE;
  const float* xp = x + (b * 128 + c) * HW_;
  const float* wp = dw_w + c * 9;
  float acc = dw_b[c];
  #pragma unroll
  for (int dy = 0; dy < 3; ++dy) {
    int sy = yy + dy - 1;
    if (sy < 0 || sy >= 96) continue;
    #pragma unroll
    for (int dx = 0; dx < 3; ++dx) {
      int sx = xx + dx - 1;
      if (sx < 0 || sx >= 96) continue;
      acc += xp[sy * 96 + sx] * wp[dy * 3 + dx];
    }
  }
  h1[i] = acc;
}

// ---------------- pointwise 1x1 + bias : NCHW in -> BHWC out ----------------
// tiled GEMM: block = 32 pixels x 128 oc, thread = 4 oc x 4 pix.
__global__ __launch_bounds__(256) void k_pw(
    const float* __restrict__ h1, const float* __restrict__ pwt,
    const float* __restrict__ pw_b, float* __restrict__ s) {
  __shared__ float samp[32 * 128];   // [p4][c][4], 16 KB
  int tid = threadIdx.x;
  int pixbase = blockIdx.x * 32;
  int b = pixbase / HW_;
  int hw0 = pixbase % HW_;

  // stage: thread (=c row) copies 32 contiguous pixels from NCHW h1
  if (tid < 128) {
    const float* hp = h1 + (size_t)(b * 128 + tid) * HW_ + hw0;
    #pragma unroll
    for (int p4 = 0; p4 < 8; ++p4) {
      float4 v = *(const float4*)(hp + p4 * 4);
      *(float4*)&samp[p4 * 512 + tid * 4] = v;   // lane-contiguous 16B: no conflicts
    }
  }
  __syncthreads();

  int to = tid & 31;    // oc = 4*to
  int tp = tid >> 5;    // pixel group p4 = tp
  float acc[4][4];
  #pragma unroll
  for (int i = 0; i < 4; ++i)
    #pragma unroll
    for (int j = 0; j < 4; ++j) acc[i][j] = 0.f;

  const float4* wp4 = (const float4*)pwt;
  const float4* sp4 = (const float4*)&samp[tp * 512];
  #pragma unroll 8
  for (int c = 0; c < 128; ++c) {
    float4 w4 = wp4[c * 32 + to];   // coalesced 512B across 32 lanes, L1-hot
    float4 s4 = sp4[c];             // broadcast, conflict-free
    float wr[4] = {w4.x, w4.y, w4.z, w4.w};
    float sr[4] = {s4.x, s4.y, s4.z, s4.w};
    #pragma unroll
    for (int i = 0; i < 4; ++i)
      #pragma unroll
      for (int j = 0; j < 4; ++j)
        acc[i][j] = fmaf(wr[i], sr[j], acc[i][j]);
  }

  float b0 = pw_b[4 * to + 0], b1 = pw_b[4 * to + 1],
        b2 = pw_b[4 * to + 2], b3 = pw_b[4 * to + 3];
  #pragma unroll
  for (int j = 0; j < 4; ++j) {
    int pix = pixbase + 4 * tp + j;
    float4 v = make_float4(acc[0][j] + b0, acc[1][j] + b1, acc[2][j] + b2, acc[3][j] + b3);
    *(float4*)(s + (size_t)pix * 128 + 4 * to) = v;
  }
}

// ---------------- InstanceNorm stats (per b,c over HW) ----------------
__global__ void k_instats(const float* __restrict__ s, float* __restrict__ ist) {
  int b = blockIdx.x / 36; int tile = blockIdx.x % 36;
  int c = threadIdx.x & 127; int half = threadIdx.x >> 7;
  const float* base = s + (size_t)(b * HW_ + tile * 256) * 128;
  float sum = 0.f, sq = 0.f;
  for (int p = half; p < 256; p += 2) {
    float v = base[p * 128 + c];
    sum += v; sq += v * v;
  }
  __shared__ float r1[256], r2[256];
  r1[threadIdx.x] = sum; r2[threadIdx.x] = sq;
  __syncthreads();
  if (half == 0) {
    atomicAdd(&ist[(b * 128 + c) * 2],     r1[c] + r1[c + 128]);
    atomicAdd(&ist[(b * 128 + c) * 2 + 1], r2[c] + r2[c + 128]);
  }
}

__global__ void k_infin(const float* __restrict__ ist, float* __restrict__ ifin) {
  int i = blockIdx.x * 256 + threadIdx.x;
  if (i >= 512) return;
  float mean = ist[2 * i] * (1.f / 9216.f);
  float var  = ist[2 * i + 1] * (1.f / 9216.f) - mean * mean;
  ifin[2 * i] = mean;
  ifin[2 * i + 1] = rsqrtf(var + 1e-5f);
}

// ---------------- apply IN + ReLU in place ----------------
__global__ void k_inapply(float* __restrict__ s, const float* __restrict__ ifin) {
  int i = blockIdx.x * 256 + threadIdx.x;
  if (i >= BHWC) return;
  int c = i & 127; int b = i / BATCH_STRIDE;
  float m = ifin[(b * 128 + c) * 2], r = ifin[(b * 128 + c) * 2 + 1];
  float v = (s[i] - m) * r;
  s[i] = v > 0.f ? v : 0.f;
}

// ---------------- offset conv, tap-split: po[k][oc][pix] partials ----------------
// thread = (pixel, tap); grid (NPIX/256, 9) = 1296 blocks -> ~20 waves/CU.
__global__ __launch_bounds__(256) void k_off_tap(
    const float* __restrict__ s, const float* __restrict__ wo,
    float* __restrict__ po) {
  int k = blockIdx.y;
  int pix = blockIdx.x * 256 + threadIdx.x;
  int b = pix / HW_; int hw = pix % HW_; int y = hw / 96; int x = hw % 96;

  float acc[18];
  #pragma unroll
  for (int oc = 0; oc < 18; ++oc) acc[oc] = 0.f;

  int sy = y + k / 3 - 1;
  int sx = x + k % 3 - 1;
  if (sy >= 0 && sy < 96 && sx >= 0 && sx < 96) {
    const float4* win = (const float4*)(s + (size_t)b * BATCH_STRIDE + (sy * 96 + sx) * 128);
    const float4* wk  = (const float4*)(wo + k * 2304);
    #pragma unroll 4
    for (int c4 = 0; c4 < 32; ++c4) {
      float4 a = win[c4];
      #pragma unroll
      for (int oc = 0; oc < 18; ++oc) {
        float4 w = wk[c4 * 18 + oc];
        acc[oc] = fmaf(a.x, w.x, acc[oc]);
        acc[oc] = fmaf(a.y, w.y, acc[oc]);
        acc[oc] = fmaf(a.z, w.z, acc[oc]);
        acc[oc] = fmaf(a.w, w.w, acc[oc]);
      }
    }
  }
  float* pp = po + (size_t)k * 18 * NPIX + pix;
  #pragma unroll
  for (int oc = 0; oc < 18; ++oc) pp[(size_t)oc * NPIX] = acc[oc];   // coalesced
}

// ---------------- offset reduce: off[oc][pix] = bias + sum_k po ----------------
__global__ void k_off_red(const float* __restrict__ po, const float* __restrict__ off_b,
                          float* __restrict__ off) {
  int i = blockIdx.x * 256 + threadIdx.x;   // i = oc*NPIX + pix
  if (i >= 18 * NPIX) return;
  int oc = i / NPIX;
  float a = off_b[oc];
  #pragma unroll
  for (int k = 0; k < 9; ++k) a += po[(size_t)k * 18 * NPIX + i];
  off[i] = a;
}

// ---------------- deform sampling: bilinear once per (pixel,tap,c), bf16 out ----
// thread = (pixel, tap); grid (PIX_CHUNK/256, 9). Output in MFMA B-frag order:
// samp[pixblk][kslice=k*4+kk][lane=g*16+lp][j]  (bf16), pixel=pixblk*16+lp,
// c = kk*32 + g*8 + j.  Massive occupancy hides gather latency.
__global__ __launch_bounds__(256) void k_sample(
    const float* __restrict__ s, const float* __restrict__ off,
    short* __restrict__ samp, int p0) {
  int k  = blockIdx.y;
  int pl = blockIdx.x * 256 + threadIdx.x;   // local pixel within chunk
  int pix = p0 + pl;
  int b = pix / HW_; int hw = pix % HW_; int y = hw / 96; int x = hw % 96;
  const float* sb = s + (size_t)b * BATCH_STRIDE;

  float dy = off[(size_t)(2 * k)     * NPIX + pix];   // coalesced
  float dx = off[(size_t)(2 * k + 1) * NPIX + pix];   // coalesced
  float py = (float)y + (float)(k / 3 - 1) + dy;
  float px = (float)x + (float)(k % 3 - 1) + dx;
  float y0f = floorf(py), x0f = floorf(px);
  float ly = py - y0f, lx = px - x0f;
  int y0 = (int)y0f, x0 = (int)x0f;
  bool vy0 = (y0 >= 0) && (y0 < 96), vy1 = (y0 + 1 >= 0) && (y0 + 1 < 96);
  bool vx0 = (x0 >= 0) && (x0 < 96), vx1 = (x0 + 1 >= 0) && (x0 + 1 < 96);
  float w00 = (vy0 && vx0) ? (1.f - ly) * (1.f - lx) : 0.f;
  float w01 = (vy0 && vx1) ? (1.f - ly) * lx : 0.f;
  float w10 = (vy1 && vx0) ? ly * (1.f - lx) : 0.f;
  float w11 = (vy1 && vx1) ? ly * lx : 0.f;
  int yc0 = min(max(y0, 0), 95), yc1 = min(max(y0 + 1, 0), 95);
  int xc0 = min(max(x0, 0), 95), xc1 = min(max(x0 + 1, 0), 95);
  const float* p00 = sb + (yc0 * 96 + xc0) * 128;
  const float* p01 = sb + (yc0 * 96 + xc1) * 128;
  const float* p10 = sb + (yc1 * 96 + xc0) * 128;
  const float* p11 = sb + (yc1 * 96 + xc1) * 128;

  int pixblk = pl >> 4, lp = pl & 15;
  bfrag8* sp = (bfrag8*)samp;
  size_t base = ((size_t)pixblk * 36 + k * 4) * 64 + lp;   // + kk*64 + g*16

  #pragma unroll 4
  for (int c8 = 0; c8 < 16; ++c8) {
    int c = c8 * 8;
    float4 a0 = *(const float4*)(p00 + c), a1 = *(const float4*)(p00 + c + 4);
    float4 b0 = *(const float4*)(p01 + c), b1 = *(const float4*)(p01 + c + 4);
    float4 c0 = *(const float4*)(p10 + c), c1 = *(const float4*)(p10 + c + 4);
    float4 d0 = *(const float4*)(p11 + c), d1 = *(const float4*)(p11 + c + 4);
    bfrag8 r;
    r[0] = f2bf(a0.x * w00 + b0.x * w01 + c0.x * w10 + d0.x * w11);
    r[1] = f2bf(a0.y * w00 + b0.y * w01 + c0.y * w10 + d0.y * w11);
    r[2] = f2bf(a0.z * w00 + b0.z * w01 + c0.z * w10 + d0.z * w11);
    r[3] = f2bf(a0.w * w00 + b0.w * w01 + c0.w * w10 + d0.w * w11);
    r[4] = f2bf(a1.x * w00 + b1.x * w01 + c1.x * w10 + d1.x * w11);
    r[5] = f2bf(a1.y * w00 + b1.y * w01 + c1.y * w10 + d1.y * w11);
    r[6] = f2bf(a1.z * w00 + b1.z * w01 + c1.z * w10 + d1.z * w11);
    r[7] = f2bf(a1.w * w00 + b1.w * w01 + c1.w * w10 + d1.w * w11);
    int kk = c8 >> 2, g = c8 & 3;
    sp[base + kk * 64 + g * 16] = r;
  }
}

// ---------------- deform GEMM: D[oc][pix] = sum_K W*samp, bf16 MFMA ----------
// block = 128 oc x 64 pix, 4 waves (2 oc-groups x 2 pix-groups);
// wave = 64 oc (4 mt) x 32 pix (2 pixblk). All frag loads coalesced 1KB blocks.
// Epilogue fuses bias + GroupNorm partial sums (removes k_gnstats).
__global__ __launch_bounds__(256) void k_degemm(
    const short* __restrict__ samp, const short* __restrict__ wtb,
    const float* __restrict__ de_b, float* __restrict__ d,
    float* __restrict__ gst, int p0) {
  int tid = threadIdx.x;
  int lane = tid & 63, wv = tid >> 6;
  int pixblk = blockIdx.x * 4 + (wv & 1) * 2;   // local; covers pixblk, pixblk+1
  int mtg0 = (wv >> 1) * 4;                     // 4 consecutive 16-oc tiles
  const bfrag8* sp = (const bfrag8*)samp;
  const bfrag8* wp = (const bfrag8*)wtb;

  f32x4 acc[4][2];
  #pragma unroll
  for (int m = 0; m < 4; ++m)
    #pragma unroll
    for (int n = 0; n < 2; ++n) acc[m][n] = (f32x4){0.f, 0.f, 0.f, 0.f};

  #pragma unroll 4
  for (int ks = 0; ks < 36; ++ks) {
    bfrag8 bf0 = sp[((size_t)(pixblk + 0) * 36 + ks) * 64 + lane];
    bfrag8 bf1 = sp[((size_t)(pixblk + 1) * 36 + ks) * 64 + lane];
    int k = ks >> 2, kk = ks & 3;
    #pragma unroll
    for (int m = 0; m < 4; ++m) {
      bfrag8 af = wp[((size_t)((k * 8 + mtg0 + m) * 4 + kk)) * 64 + lane];
      acc[m][0] = __builtin_amdgcn_mfma_f32_16x16x32_bf16(af, bf0, acc[m][0], 0, 0, 0);
      acc[m][1] = __builtin_amdgcn_mfma_f32_16x16x32_bf16(af, bf1, acc[m][1], 0, 0, 0);
    }
  }

  // epilogue: bias + store + GN partials. D: lane l reg r -> oc_local=(l>>4)*4+r, pix=l&15
  int g = lane >> 4, lp = lane & 15;
  float lsum = 0.f, lsq = 0.f;
  #pragma unroll
  for (int m = 0; m < 4; ++m) {
    int oc = (mtg0 + m) * 16 + g * 4;
    float4 bias = *(const float4*)(de_b + oc);
    #pragma unroll
    for (int n = 0; n < 2; ++n) {
      int pix = p0 + (pixblk + n) * 16 + lp;
      f32x4 a = acc[m][n];
      float4 v = make_float4(a[0] + bias.x, a[1] + bias.y, a[2] + bias.z, a[3] + bias.w);
      *(float4*)(d + (size_t)pix * 128 + oc) = v;
      lsum += v.x + v.y + v.z + v.w;
      lsq  += v.x * v.x + v.y * v.y + v.z * v.z + v.w * v.w;
    }
  }
  __shared__ float r1[256], r2[256];
  r1[tid] = lsum; r2[tid] = lsq;
  __syncthreads();
  for (int st = 128; st > 0; st >>= 1) {
    if (tid < st) { r1[tid] += r1[tid + st]; r2[tid] += r2[tid + st]; }
    __syncthreads();
  }
  if (tid == 0) {
    int b = (p0 + blockIdx.x * 64) / HW_;
    atomicAdd(&gst[b * 2],     r1[0]);
    atomicAdd(&gst[b * 2 + 1], r2[0]);
  }
}

__global__ void k_gnfin(const float* __restrict__ gst, float* __restrict__ gfin) {
  int b = threadIdx.x;
  if (b >= 4) return;
  const float invN = 1.f / (float)BATCH_STRIDE;
  float mean = gst[2 * b] * invN;
  float var  = gst[2 * b + 1] * invN - mean * mean;
  gfin[2 * b] = mean;
  gfin[2 * b + 1] = rsqrtf(var + 1e-5f);
}

// ---------------- final: GN affine + sigmoid gate, BHWC -> NCHW ----------------
__global__ void k_final(const float* __restrict__ d, const float* __restrict__ s,
                        const float* __restrict__ gfin, const float* __restrict__ gn_w,
                        const float* __restrict__ gn_b, float* __restrict__ out) {
  int i = blockIdx.x * 256 + threadIdx.x;   // NCHW order -> coalesced writes
  if (i >= BHWC) return;
  int xx = i % 96; int yy = (i / 96) % 96; int c = (i / HW_) % 128; int b = i / BATCH_STRIDE;
  size_t cl = (size_t)(b * HW_ + yy * 96 + xx) * 128 + c;
  float dv = d[cl], sv = s[cl];
  float dn = (dv - gfin[2 * b]) * gfin[2 * b + 1] * gn_w[c] + gn_b[c];
  float g = 1.f / (1.f + expf(-dn));
  out[i] = g * sv + sv;
}

extern "C" void kernel_launch(void* const* d_in, const int* in_sizes, int n_in,
                              void* d_out, int out_size, void* d_ws, size_t ws_size,
                              hipStream_t stream) {
  (void)in_sizes; (void)n_in; (void)out_size; (void)ws_size;
  const float* x     = (const float*)d_in[0];
  const float* dw_w  = (const float*)d_in[1];
  const float* dw_b  = (const float*)d_in[2];
  const float* pw_w  = (const float*)d_in[3];
  const float* pw_b  = (const float*)d_in[4];
  const float* off_w = (const float*)d_in[5];
  const float* off_b = (const float*)d_in[6];
  const float* de_w  = (const float*)d_in[7];
  const float* de_b  = (const float*)d_in[8];
  const float* gn_w  = (const float*)d_in[9];
  const float* gn_b  = (const float*)d_in[10];
  float* out = (float*)d_out;

  float* ws   = (float*)d_ws;
  float* h1   = ws;                 // NCHW depthwise out; reused as deform out d (BHWC)
  float* s    = h1 + BHWC;          // BHWC shortcut
  float* off  = s + BHWC;           // [18][NPIX] offsets (oc-major)
  short* wtb  = (short*)(off + NPIX * 18);  // bf16 A-frag packed de_w (147456 bf16)
  float* wo   = off + NPIX * 18 + 73728;    // [9][32][18][4]
  float* pwt  = wo + 20736;         // [c][oc] 16384
  float* ist  = pwt + 16384;        // [B][C][2] sum,sumsq
  float* ifin = ist + 1024;         // [B][C][2] mean,rstd
  float* gst  = ifin + 1024;        // [B][2]
  float* gfin = gst + 8;            // [B][2]
  short* samp = (short*)(gfin + 8); // bf16 B-frag samples, PIX_CHUNK*1152 (42.5 MB)
  float* po   = (float*)samp;       // overlay: [9][18][NPIX] partials (24 MB), dead before k_sample

  // zero the atomic accumulators (ist..gfin region)
  hipMemsetAsync(ist, 0, (1024 + 1024 + 8 + 8) * sizeof(float), stream);

  k_transpose_w<<<576, 256, 0, stream>>>(de_w, off_w, pw_w, wtb, wo, pwt);
  k_dw<<<BHWC / 256, 256, 0, stream>>>(x, dw_w, dw_b, h1);
  k_pw<<<NPIX / 32, 256, 0, stream>>>(h1, pwt, pw_b, s);
  k_instats<<<4 * 36, 256, 0, stream>>>(s, ist);
  k_infin<<<2, 256, 0, stream>>>(ist, ifin);
  k_inapply<<<BHWC / 256, 256, 0, stream>>>(s, ifin);

  dim3 ogrid(NPIX / 256, 9);
  k_off_tap<<<ogrid, 256, 0, stream>>>(s, wo, po);
  k_off_red<<<(18 * NPIX) / 256, 256, 0, stream>>>(po, off_b, off);

  dim3 sgrid(PIX_CHUNK / 256, 9);
  for (int chunk = 0; chunk < 2; ++chunk) {
    int p0 = chunk * PIX_CHUNK;
    k_sample<<<sgrid, 256, 0, stream>>>(s, off, samp, p0);
    k_degemm<<<PIX_CHUNK / 64, 256, 0, stream>>>(samp, wtb, de_b, h1, gst, p0);
  }

  k_gnfin<<<1, 64, 0, stream>>>(gst, gfin);
  k_final<<<BHWC / 256, 256, 0, stream>>>(h1, s, gfin, gn_w, gn_b, out);
}

// Round 7
// 319.672 us; speedup vs baseline: 2.2963x; 1.2317x over previous
//
#include <hip/hip_runtime.h>
#include <hip/hip_bf16.h>
#include <math.h>

#define B_    4
#define C_    128
#define H_    96
#define W_    96
#define HW_   9216          // H*W
#define NPIX  36864         // B*HW
#define PIX_CHUNK 18432     // NPIX/2
#define BHWC  4718592       // B*HW*C
#define BATCH_STRIDE 1179648 // HW*C

typedef __attribute__((ext_vector_type(8))) short bfrag8;
typedef __attribute__((ext_vector_type(4))) float f32x4;

static __device__ __forceinline__ short f2bf(float f) {
  __hip_bfloat16 h = __float2bfloat16(f);
  short s;
  __builtin_memcpy(&s, &h, 2);
  return s;
}

// ---------------- weight transposes ----------------
// wtb: bf16 A-fragment order [k][mt(8)][kk(4)][lane(64)][j(8)]  (147456)
//      element: oc = mt*16 + (lane&15), c = kk*32 + (lane>>4)*8 + j, tap k
// wo:  [k][c4][oc][4]  from off_w [oc][c][k]  (9*32*18*4 = 20736)
// pwt: [c][oc]         from pw_w [oc][c]      (16384)
__global__ void k_transpose_w(const float* __restrict__ de_w,
                              const float* __restrict__ off_w,
                              const float* __restrict__ pw_w,
                              short* __restrict__ wtb, float* __restrict__ wo,
                              float* __restrict__ pwt) {
  int i = blockIdx.x * 256 + threadIdx.x;
  if (i < 147456) {
    int j  = i & 7;
    int l  = (i >> 3) & 63;
    int kk = (i >> 9) & 3;
    int mt = (i >> 11) & 7;
    int k  = i >> 14;
    int oc = mt * 16 + (l & 15);
    int c  = kk * 32 + ((l >> 4) << 3) + j;
    wtb[i] = f2bf(de_w[(oc * 128 + c) * 9 + k]);
  }
  if (i < 20736) {
    int j  = i & 3;
    int oc = (i >> 2) % 18;
    int c4 = (i / 72) % 32;
    int k  = i / 2304;
    wo[i] = off_w[(oc * 128 + c4 * 4 + j) * 9 + k];
  }
  if (i < 16384) {
    int oc = i & 127; int c = i >> 7;
    pwt[i] = pw_w[oc * 128 + c];
  }
}

// ---------------- depthwise 3x3 + bias : NCHW in -> NCHW out ----------------
__global__ void k_dw(const float* __restrict__ x, const float* __restrict__ dw_w,
                     const float* __restrict__ dw_b, float* __restrict__ h1) {
  int i = blockIdx.x * 256 + threadIdx.x;   // NCHW order, coalesced in AND out
  if (i >= BHWC) return;
  int xx = i % 96; int yy = (i / 96) % 96; int c = (i / HW_) % 128; int b = i / BATCH_STRIDE;
  const float* xp = x + (b * 128 + c) * HW_;
  const float* wp = dw_w + c * 9;
  float acc = dw_b[c];
  #pragma unroll
  for (int dy = 0; dy < 3; ++dy) {
    int sy = yy + dy - 1;
    if (sy < 0 || sy >= 96) continue;
    #pragma unroll
    for (int dx = 0; dx < 3; ++dx) {
      int sx = xx + dx - 1;
      if (sx < 0 || sx >= 96) continue;
      acc += xp[sy * 96 + sx] * wp[dy * 3 + dx];
    }
  }
  h1[i] = acc;
}

// ---------------- pointwise 1x1 + bias : NCHW in -> BHWC out ----------------
// tiled GEMM: block = 32 pixels x 128 oc, thread = 4 oc x 4 pix.
__global__ __launch_bounds__(256) void k_pw(
    const float* __restrict__ h1, const float* __restrict__ pwt,
    const float* __restrict__ pw_b, float* __restrict__ s) {
  __shared__ float samp[32 * 128];   // [p4][c][4], 16 KB
  int tid = threadIdx.x;
  int pixbase = blockIdx.x * 32;
  int b = pixbase / HW_;
  int hw0 = pixbase % HW_;

  // stage: thread (=c row) copies 32 contiguous pixels from NCHW h1
  if (tid < 128) {
    const float* hp = h1 + (size_t)(b * 128 + tid) * HW_ + hw0;
    #pragma unroll
    for (int p4 = 0; p4 < 8; ++p4) {
      float4 v = *(const float4*)(hp + p4 * 4);
      *(float4*)&samp[p4 * 512 + tid * 4] = v;   // lane-contiguous 16B: no conflicts
    }
  }
  __syncthreads();

  int to = tid & 31;    // oc = 4*to
  int tp = tid >> 5;    // pixel group p4 = tp
  float acc[4][4];
  #pragma unroll
  for (int i = 0; i < 4; ++i)
    #pragma unroll
    for (int j = 0; j < 4; ++j) acc[i][j] = 0.f;

  const float4* wp4 = (const float4*)pwt;
  const float4* sp4 = (const float4*)&samp[tp * 512];
  #pragma unroll 8
  for (int c = 0; c < 128; ++c) {
    float4 w4 = wp4[c * 32 + to];   // coalesced 512B across 32 lanes, L1-hot
    float4 s4 = sp4[c];             // broadcast, conflict-free
    float wr[4] = {w4.x, w4.y, w4.z, w4.w};
    float sr[4] = {s4.x, s4.y, s4.z, s4.w};
    #pragma unroll
    for (int i = 0; i < 4; ++i)
      #pragma unroll
      for (int j = 0; j < 4; ++j)
        acc[i][j] = fmaf(wr[i], sr[j], acc[i][j]);
  }

  float b0 = pw_b[4 * to + 0], b1 = pw_b[4 * to + 1],
        b2 = pw_b[4 * to + 2], b3 = pw_b[4 * to + 3];
  #pragma unroll
  for (int j = 0; j < 4; ++j) {
    int pix = pixbase + 4 * tp + j;
    float4 v = make_float4(acc[0][j] + b0, acc[1][j] + b1, acc[2][j] + b2, acc[3][j] + b3);
    *(float4*)(s + (size_t)pix * 128 + 4 * to) = v;
  }
}

// ---------------- InstanceNorm stats (per b,c over HW) ----------------
__global__ void k_instats(const float* __restrict__ s, float* __restrict__ ist) {
  int b = blockIdx.x / 36; int tile = blockIdx.x % 36;
  int c = threadIdx.x & 127; int half = threadIdx.x >> 7;
  const float* base = s + (size_t)(b * HW_ + tile * 256) * 128;
  float sum = 0.f, sq = 0.f;
  for (int p = half; p < 256; p += 2) {
    float v = base[p * 128 + c];
    sum += v; sq += v * v;
  }
  __shared__ float r1[256], r2[256];
  r1[threadIdx.x] = sum; r2[threadIdx.x] = sq;
  __syncthreads();
  if (half == 0) {
    atomicAdd(&ist[(b * 128 + c) * 2],     r1[c] + r1[c + 128]);
    atomicAdd(&ist[(b * 128 + c) * 2 + 1], r2[c] + r2[c + 128]);
  }
}

// ---------------- IN finalize: mean/rstd planes ----------------
__global__ void k_infin(const float* __restrict__ ist, float* __restrict__ ifm,
                        float* __restrict__ ifr) {
  int i = blockIdx.x * 256 + threadIdx.x;
  if (i >= 512) return;
  float mean = ist[2 * i] * (1.f / 9216.f);
  float var  = ist[2 * i + 1] * (1.f / 9216.f) - mean * mean;
  ifm[i] = mean;
  ifr[i] = rsqrtf(var + 1e-5f);
}

// ---------------- offset conv, tap-split, IN+ReLU on the fly --------------
// thread = (pixel, tap); grid (NPIX/256, 9).
__global__ __launch_bounds__(256) void k_off_tap(
    const float* __restrict__ s, const float* __restrict__ wo,
    const float* __restrict__ ifm, const float* __restrict__ ifr,
    float* __restrict__ po) {
  int k = blockIdx.y;
  int pix = blockIdx.x * 256 + threadIdx.x;
  int b = pix / HW_; int hw = pix % HW_; int y = hw / 96; int x = hw % 96;

  float acc[18];
  #pragma unroll
  for (int oc = 0; oc < 18; ++oc) acc[oc] = 0.f;

  int sy = y + k / 3 - 1;
  int sx = x + k % 3 - 1;
  if (sy >= 0 && sy < 96 && sx >= 0 && sx < 96) {
    const float4* win = (const float4*)(s + (size_t)b * BATCH_STRIDE + (sy * 96 + sx) * 128);
    const float4* wk  = (const float4*)(wo + k * 2304);
    const float4* m4p = (const float4*)(ifm + b * 128);
    const float4* r4p = (const float4*)(ifr + b * 128);
    #pragma unroll 4
    for (int c4 = 0; c4 < 32; ++c4) {
      float4 a = win[c4];
      float4 m = m4p[c4], r = r4p[c4];
      a.x = fmaxf((a.x - m.x) * r.x, 0.f);
      a.y = fmaxf((a.y - m.y) * r.y, 0.f);
      a.z = fmaxf((a.z - m.z) * r.z, 0.f);
      a.w = fmaxf((a.w - m.w) * r.w, 0.f);
      #pragma unroll
      for (int oc = 0; oc < 18; ++oc) {
        float4 w = wk[c4 * 18 + oc];
        acc[oc] = fmaf(a.x, w.x, acc[oc]);
        acc[oc] = fmaf(a.y, w.y, acc[oc]);
        acc[oc] = fmaf(a.z, w.z, acc[oc]);
        acc[oc] = fmaf(a.w, w.w, acc[oc]);
      }
    }
  }
  float* pp = po + (size_t)k * 18 * NPIX + pix;
  #pragma unroll
  for (int oc = 0; oc < 18; ++oc) pp[(size_t)oc * NPIX] = acc[oc];   // coalesced
}

// ---------------- offset reduce: off[oc][pix] = bias + sum_k po ----------------
__global__ void k_off_red(const float* __restrict__ po, const float* __restrict__ off_b,
                          float* __restrict__ off) {
  int i = blockIdx.x * 256 + threadIdx.x;   // i = oc*NPIX + pix
  if (i >= 18 * NPIX) return;
  int oc = i / NPIX;
  float a = off_b[oc];
  #pragma unroll
  for (int k = 0; k < 9; ++k) a += po[(size_t)k * 18 * NPIX + i];
  off[i] = a;
}

// ---------------- deform sampling: 8 lanes per pixel, IN+ReLU on the fly ----
// thread = (pixel, c-group); grid (PIX_CHUNK/32, 9). 8 lanes share one pixel's
// corner rows -> each load instr touches ~16 cache lines (vs 64 for lane=pixel).
// Corner values are relu((v-m)*r) BEFORE bilinear blend (matches reference).
// Output bf16 in MFMA B-frag order: samp[pixblk][ks=k*4+kk][lane=g*16+lp][j8],
// c = kk*32 + g*8 + j8. Thread (pl,l8) iter j: c = j*32 + l8*4 .. +4.
__global__ __launch_bounds__(256) void k_sample(
    const float* __restrict__ s, const float* __restrict__ off,
    const float* __restrict__ ifm, const float* __restrict__ ifr,
    short* __restrict__ samp, int p0) {
  int k  = blockIdx.y;
  int tid = threadIdx.x;
  int pw_ = tid >> 3;        // pixel 0..31
  int l8  = tid & 7;         // c-group
  int pl = blockIdx.x * 32 + pw_;
  int pix = p0 + pl;
  int b = pix / HW_; int hw = pix % HW_; int y = hw / 96; int x = hw % 96;
  const float* sb = s + (size_t)b * BATCH_STRIDE;

  float dy = off[(size_t)(2 * k)     * NPIX + pix];   // broadcast per 8 lanes
  float dx = off[(size_t)(2 * k + 1) * NPIX + pix];
  float py = (float)y + (float)(k / 3 - 1) + dy;
  float px = (float)x + (float)(k % 3 - 1) + dx;
  float y0f = floorf(py), x0f = floorf(px);
  float ly = py - y0f, lx = px - x0f;
  int y0 = (int)y0f, x0 = (int)x0f;
  bool vy0 = (y0 >= 0) && (y0 < 96), vy1 = (y0 + 1 >= 0) && (y0 + 1 < 96);
  bool vx0 = (x0 >= 0) && (x0 < 96), vx1 = (x0 + 1 >= 0) && (x0 + 1 < 96);
  float w00 = (vy0 && vx0) ? (1.f - ly) * (1.f - lx) : 0.f;
  float w01 = (vy0 && vx1) ? (1.f - ly) * lx : 0.f;
  float w10 = (vy1 && vx0) ? ly * (1.f - lx) : 0.f;
  float w11 = (vy1 && vx1) ? ly * lx : 0.f;
  int yc0 = min(max(y0, 0), 95), yc1 = min(max(y0 + 1, 0), 95);
  int xc0 = min(max(x0, 0), 95), xc1 = min(max(x0 + 1, 0), 95);
  const float* p00 = sb + (yc0 * 96 + xc0) * 128;
  const float* p01 = sb + (yc0 * 96 + xc1) * 128;
  const float* p10 = sb + (yc1 * 96 + xc0) * 128;
  const float* p11 = sb + (yc1 * 96 + xc1) * 128;

  int pixblk = pl >> 4, lp = pl & 15;
  int g = l8 >> 1, hf = l8 & 1;

  #pragma unroll
  for (int j = 0; j < 4; ++j) {
    int c = j * 32 + l8 * 4;
    float4 m4 = *(const float4*)(ifm + b * 128 + c);
    float4 r4 = *(const float4*)(ifr + b * 128 + c);
    float4 a  = *(const float4*)(p00 + c);
    float4 bq = *(const float4*)(p01 + c);
    float4 cq = *(const float4*)(p10 + c);
    float4 dq = *(const float4*)(p11 + c);
    // relu-normalize each corner, then blend
    float o0 = fmaxf((a.x - m4.x) * r4.x, 0.f) * w00 + fmaxf((bq.x - m4.x) * r4.x, 0.f) * w01
             + fmaxf((cq.x - m4.x) * r4.x, 0.f) * w10 + fmaxf((dq.x - m4.x) * r4.x, 0.f) * w11;
    float o1 = fmaxf((a.y - m4.y) * r4.y, 0.f) * w00 + fmaxf((bq.y - m4.y) * r4.y, 0.f) * w01
             + fmaxf((cq.y - m4.y) * r4.y, 0.f) * w10 + fmaxf((dq.y - m4.y) * r4.y, 0.f) * w11;
    float o2 = fmaxf((a.z - m4.z) * r4.z, 0.f) * w00 + fmaxf((bq.z - m4.z) * r4.z, 0.f) * w01
             + fmaxf((cq.z - m4.z) * r4.z, 0.f) * w10 + fmaxf((dq.z - m4.z) * r4.z, 0.f) * w11;
    float o3 = fmaxf((a.w - m4.w) * r4.w, 0.f) * w00 + fmaxf((bq.w - m4.w) * r4.w, 0.f) * w01
             + fmaxf((cq.w - m4.w) * r4.w, 0.f) * w10 + fmaxf((dq.w - m4.w) * r4.w, 0.f) * w11;
    short4 st = make_short4(f2bf(o0), f2bf(o1), f2bf(o2), f2bf(o3));
    size_t si = (((size_t)pixblk * 36 + k * 4 + j) * 64 + g * 16 + lp) * 8 + hf * 4;
    *(short4*)(samp + si) = st;
  }
}

// ---------------- deform GEMM: D[oc][pix] = sum_K W*samp, bf16 MFMA ----------
// block = 128 oc x 64 pix, 4 waves; wave = 64 oc (4 mt) x 32 pix (2 pixblk).
// Epilogue fuses bias + GroupNorm partial sums.
__global__ __launch_bounds__(256) void k_degemm(
    const short* __restrict__ samp, const short* __restrict__ wtb,
    const float* __restrict__ de_b, float* __restrict__ d,
    float* __restrict__ gst, int p0) {
  int tid = threadIdx.x;
  int lane = tid & 63, wv = tid >> 6;
  int pixblk = blockIdx.x * 4 + (wv & 1) * 2;   // local; covers pixblk, pixblk+1
  int mtg0 = (wv >> 1) * 4;                     // 4 consecutive 16-oc tiles
  const bfrag8* sp = (const bfrag8*)samp;
  const bfrag8* wp = (const bfrag8*)wtb;

  f32x4 acc[4][2];
  #pragma unroll
  for (int m = 0; m < 4; ++m)
    #pragma unroll
    for (int n = 0; n < 2; ++n) acc[m][n] = (f32x4){0.f, 0.f, 0.f, 0.f};

  #pragma unroll 4
  for (int ks = 0; ks < 36; ++ks) {
    bfrag8 bf0 = sp[((size_t)(pixblk + 0) * 36 + ks) * 64 + lane];
    bfrag8 bf1 = sp[((size_t)(pixblk + 1) * 36 + ks) * 64 + lane];
    int k = ks >> 2, kk = ks & 3;
    #pragma unroll
    for (int m = 0; m < 4; ++m) {
      bfrag8 af = wp[((size_t)((k * 8 + mtg0 + m) * 4 + kk)) * 64 + lane];
      acc[m][0] = __builtin_amdgcn_mfma_f32_16x16x32_bf16(af, bf0, acc[m][0], 0, 0, 0);
      acc[m][1] = __builtin_amdgcn_mfma_f32_16x16x32_bf16(af, bf1, acc[m][1], 0, 0, 0);
    }
  }

  // epilogue: bias + store + GN partials. D: lane l reg r -> oc_local=(l>>4)*4+r, pix=l&15
  int g = lane >> 4, lp = lane & 15;
  float lsum = 0.f, lsq = 0.f;
  #pragma unroll
  for (int m = 0; m < 4; ++m) {
    int oc = (mtg0 + m) * 16 + g * 4;
    float4 bias = *(const float4*)(de_b + oc);
    #pragma unroll
    for (int n = 0; n < 2; ++n) {
      int pix = p0 + (pixblk + n) * 16 + lp;
      f32x4 a = acc[m][n];
      float4 v = make_float4(a[0] + bias.x, a[1] + bias.y, a[2] + bias.z, a[3] + bias.w);
      *(float4*)(d + (size_t)pix * 128 + oc) = v;
      lsum += v.x + v.y + v.z + v.w;
      lsq  += v.x * v.x + v.y * v.y + v.z * v.z + v.w * v.w;
    }
  }
  __shared__ float r1[256], r2[256];
  r1[tid] = lsum; r2[tid] = lsq;
  __syncthreads();
  for (int st = 128; st > 0; st >>= 1) {
    if (tid < st) { r1[tid] += r1[tid + st]; r2[tid] += r2[tid + st]; }
    __syncthreads();
  }
  if (tid == 0) {
    int b = (p0 + blockIdx.x * 64) / HW_;
    atomicAdd(&gst[b * 2],     r1[0]);
    atomicAdd(&gst[b * 2 + 1], r2[0]);
  }
}

__global__ void k_gnfin(const float* __restrict__ gst, float* __restrict__ gfin) {
  int b = threadIdx.x;
  if (b >= 4) return;
  const float invN = 1.f / (float)BATCH_STRIDE;
  float mean = gst[2 * b] * invN;
  float var  = gst[2 * b + 1] * invN - mean * mean;
  gfin[2 * b] = mean;
  gfin[2 * b + 1] = rsqrtf(var + 1e-5f);
}

// ---------------- final: GN + sigmoid gate + shortcut, LDS transpose --------
// block = 32 px x 128 c; phase 1 reads d,s BHWC-coalesced, computes result,
// stages transposed in padded LDS; phase 2 writes NCHW-coalesced.
__global__ __launch_bounds__(256) void k_final(
    const float* __restrict__ d, const float* __restrict__ s,
    const float* __restrict__ ifm, const float* __restrict__ ifr,
    const float* __restrict__ gfin, const float* __restrict__ gn_w,
    const float* __restrict__ gn_b, float* __restrict__ out) {
  __shared__ float t[128 * 33];   // [c][33] pad -> conflict-free both phases
  int tid = threadIdx.x;
  int pixbase = blockIdx.x * 32;
  int b = pixbase / HW_;
  int hw0 = pixbase % HW_;
  float gm = gfin[2 * b], gr = gfin[2 * b + 1];

  int px0 = tid >> 3;            // pixel 0..31
  int c0  = (tid & 7) * 16;      // 16 channels
  const float* dp = d + ((size_t)(pixbase + px0)) * 128;
  const float* sp = s + ((size_t)(pixbase + px0)) * 128;
  #pragma unroll
  for (int q = 0; q < 4; ++q) {
    int c = c0 + q * 4;
    float4 dv = *(const float4*)(dp + c);
    float4 sv = *(const float4*)(sp + c);
    float4 m4 = *(const float4*)(ifm + b * 128 + c);
    float4 r4 = *(const float4*)(ifr + b * 128 + c);
    float4 w4 = *(const float4*)(gn_w + c);
    float4 b4 = *(const float4*)(gn_b + c);
    float svn, dn, gg;
    svn = fmaxf((sv.x - m4.x) * r4.x, 0.f);
    dn  = (dv.x - gm) * gr * w4.x + b4.x;
    gg  = 1.f / (1.f + expf(-dn));
    t[(c + 0) * 33 + px0] = svn * (1.f + gg);
    svn = fmaxf((sv.y - m4.y) * r4.y, 0.f);
    dn  = (dv.y - gm) * gr * w4.y + b4.y;
    gg  = 1.f / (1.f + expf(-dn));
    t[(c + 1) * 33 + px0] = svn * (1.f + gg);
    svn = fmaxf((sv.z - m4.z) * r4.z, 0.f);
    dn  = (dv.z - gm) * gr * w4.z + b4.z;
    gg  = 1.f / (1.f + expf(-dn));
    t[(c + 2) * 33 + px0] = svn * (1.f + gg);
    svn = fmaxf((sv.w - m4.w) * r4.w, 0.f);
    dn  = (dv.w - gm) * gr * w4.w + b4.w;
    gg  = 1.f / (1.f + expf(-dn));
    t[(c + 3) * 33 + px0] = svn * (1.f + gg);
  }
  __syncthreads();
  if (tid < 128) {
    float* op = out + (size_t)(b * 128 + tid) * HW_ + hw0;
    #pragma unroll
    for (int p4 = 0; p4 < 8; ++p4) {
      float4 v = make_float4(t[tid * 33 + p4 * 4], t[tid * 33 + p4 * 4 + 1],
                             t[tid * 33 + p4 * 4 + 2], t[tid * 33 + p4 * 4 + 3]);
      *(float4*)(op + p4 * 4) = v;
    }
  }
}

extern "C" void kernel_launch(void* const* d_in, const int* in_sizes, int n_in,
                              void* d_out, int out_size, void* d_ws, size_t ws_size,
                              hipStream_t stream) {
  (void)in_sizes; (void)n_in; (void)out_size; (void)ws_size;
  const float* x     = (const float*)d_in[0];
  const float* dw_w  = (const float*)d_in[1];
  const float* dw_b  = (const float*)d_in[2];
  const float* pw_w  = (const float*)d_in[3];
  const float* pw_b  = (const float*)d_in[4];
  const float* off_w = (const float*)d_in[5];
  const float* off_b = (const float*)d_in[6];
  const float* de_w  = (const float*)d_in[7];
  const float* de_b  = (const float*)d_in[8];
  const float* gn_w  = (const float*)d_in[9];
  const float* gn_b  = (const float*)d_in[10];
  float* out = (float*)d_out;

  float* ws   = (float*)d_ws;
  float* h1   = ws;                 // NCHW depthwise out; reused as deform out d (BHWC)
  float* s    = h1 + BHWC;          // BHWC raw pw output (normalized on the fly)
  float* off  = s + BHWC;           // [18][NPIX] offsets (oc-major)
  short* wtb  = (short*)(off + NPIX * 18);  // bf16 A-frag packed de_w (147456 bf16)
  float* wo   = off + NPIX * 18 + 73728;    // [9][32][18][4]
  float* pwt  = wo + 20736;         // [c][oc] 16384
  float* ist  = pwt + 16384;        // [B][C][2] sum,sumsq
  float* ifm  = ist + 1024;         // [B][C] mean
  float* ifr  = ifm + 512;          // [B][C] rstd
  float* gst  = ifr + 512;          // [B][2]
  float* gfin = gst + 8;            // [B][2]
  short* samp = (short*)(gfin + 8); // bf16 B-frag samples, PIX_CHUNK*1152 (42.5 MB)
  float* po   = (float*)samp;       // overlay: [9][18][NPIX] partials (24 MB), dead before k_sample

  // zero the atomic accumulators (ist..gfin region)
  hipMemsetAsync(ist, 0, (1024 + 512 + 512 + 8 + 8) * sizeof(float), stream);

  k_transpose_w<<<576, 256, 0, stream>>>(de_w, off_w, pw_w, wtb, wo, pwt);
  k_dw<<<BHWC / 256, 256, 0, stream>>>(x, dw_w, dw_b, h1);
  k_pw<<<NPIX / 32, 256, 0, stream>>>(h1, pwt, pw_b, s);
  k_instats<<<4 * 36, 256, 0, stream>>>(s, ist);
  k_infin<<<2, 256, 0, stream>>>(ist, ifm, ifr);

  dim3 ogrid(NPIX / 256, 9);
  k_off_tap<<<ogrid, 256, 0, stream>>>(s, wo, ifm, ifr, po);
  k_off_red<<<(18 * NPIX) / 256, 256, 0, stream>>>(po, off_b, off);

  dim3 sgrid(PIX_CHUNK / 32, 9);
  for (int chunk = 0; chunk < 2; ++chunk) {
    int p0 = chunk * PIX_CHUNK;
    k_sample<<<sgrid, 256, 0, stream>>>(s, off, ifm, ifr, samp, p0);
    k_degemm<<<PIX_CHUNK / 64, 256, 0, stream>>>(samp, wtb, de_b, h1, gst, p0);
  }

  k_gnfin<<<1, 64, 0, stream>>>(gst, gfin);
  k_final<<<NPIX / 32, 256, 0, stream>>>(h1, s, ifm, ifr, gfin, gn_w, gn_b, out);
}

// Round 8
// 289.537 us; speedup vs baseline: 2.5353x; 1.1041x over previous
//
#include <hip/hip_runtime.h>
#include <hip/hip_bf16.h>
#include <math.h>

#define B_    4
#define C_    128
#define H_    96
#define W_    96
#define HW_   9216          // H*W
#define NPIX  36864         // B*HW
#define PIX_CHUNK 18432     // NPIX/2
#define BHWC  4718592       // B*HW*C
#define BATCH_STRIDE 1179648 // HW*C

typedef __attribute__((ext_vector_type(8))) short bfrag8;
typedef __attribute__((ext_vector_type(4))) float f32x4;

static __device__ __forceinline__ short f2bf(float f) {
  __hip_bfloat16 h = __float2bfloat16(f);
  short s;
  __builtin_memcpy(&s, &h, 2);
  return s;
}
static __device__ __forceinline__ float bf2f(short s) {
  unsigned u = ((unsigned)(unsigned short)s) << 16;
  float f;
  __builtin_memcpy(&f, &u, 4);
  return f;
}

// ---------------- weight transposes ----------------
// wtb: bf16 A-frag order [k][mt(8)][kk(4)][lane(64)][j(8)] for de_w (147456)
// wob: bf16 A-frag order [k][mt(2)][kk(4)][lane(64)][j(8)] for off_w (36864),
//      oc = mt*16+(lane&15) (zero-padded for oc>=18), c = kk*32+(lane>>4)*8+j
// pwt: [c][oc] from pw_w [oc][c] (16384)
__global__ void k_transpose_w(const float* __restrict__ de_w,
                              const float* __restrict__ off_w,
                              const float* __restrict__ pw_w,
                              short* __restrict__ wtb, short* __restrict__ wob,
                              float* __restrict__ pwt) {
  int i = blockIdx.x * 256 + threadIdx.x;
  if (i < 147456) {
    int j  = i & 7;
    int l  = (i >> 3) & 63;
    int kk = (i >> 9) & 3;
    int mt = (i >> 11) & 7;
    int k  = i >> 14;
    int oc = mt * 16 + (l & 15);
    int c  = kk * 32 + ((l >> 4) << 3) + j;
    wtb[i] = f2bf(de_w[(oc * 128 + c) * 9 + k]);
  }
  if (i < 36864) {
    int j  = i & 7;
    int l  = (i >> 3) & 63;
    int kk = (i >> 9) & 3;
    int mt = (i >> 11) & 1;
    int k  = i >> 12;
    int oc = mt * 16 + (l & 15);
    int c  = kk * 32 + ((l >> 4) << 3) + j;
    wob[i] = (oc < 18) ? f2bf(off_w[(oc * 128 + c) * 9 + k]) : (short)0;
  }
  if (i < 16384) {
    int oc = i & 127; int c = i >> 7;
    pwt[i] = pw_w[oc * 128 + c];
  }
}

// ---------------- depthwise 3x3 + bias : NCHW in -> NCHW out ----------------
__global__ void k_dw(const float* __restrict__ x, const float* __restrict__ dw_w,
                     const float* __restrict__ dw_b, float* __restrict__ h1) {
  int i = blockIdx.x * 256 + threadIdx.x;   // NCHW order, coalesced in AND out
  if (i >= BHWC) return;
  int xx = i % 96; int yy = (i / 96) % 96; int c = (i / HW_) % 128; int b = i / BATCH_STRIDE;
  const float* xp = x + (b * 128 + c) * HW_;
  const float* wp = dw_w + c * 9;
  float acc = dw_b[c];
  #pragma unroll
  for (int dy = 0; dy < 3; ++dy) {
    int sy = yy + dy - 1;
    if (sy < 0 || sy >= 96) continue;
    #pragma unroll
    for (int dx = 0; dx < 3; ++dx) {
      int sx = xx + dx - 1;
      if (sx < 0 || sx >= 96) continue;
      acc += xp[sy * 96 + sx] * wp[dy * 3 + dx];
    }
  }
  h1[i] = acc;
}

// ---------------- pointwise 1x1 + bias : NCHW in -> BHWC out ----------------
// tiled GEMM: block = 32 pixels x 128 oc, thread = 4 oc x 4 pix.
__global__ __launch_bounds__(256) void k_pw(
    const float* __restrict__ h1, const float* __restrict__ pwt,
    const float* __restrict__ pw_b, float* __restrict__ s) {
  __shared__ float samp[32 * 128];   // [p4][c][4], 16 KB
  int tid = threadIdx.x;
  int pixbase = blockIdx.x * 32;
  int b = pixbase / HW_;
  int hw0 = pixbase % HW_;

  if (tid < 128) {
    const float* hp = h1 + (size_t)(b * 128 + tid) * HW_ + hw0;
    #pragma unroll
    for (int p4 = 0; p4 < 8; ++p4) {
      float4 v = *(const float4*)(hp + p4 * 4);
      *(float4*)&samp[p4 * 512 + tid * 4] = v;
    }
  }
  __syncthreads();

  int to = tid & 31;    // oc = 4*to
  int tp = tid >> 5;    // pixel group p4 = tp
  float acc[4][4];
  #pragma unroll
  for (int i = 0; i < 4; ++i)
    #pragma unroll
    for (int j = 0; j < 4; ++j) acc[i][j] = 0.f;

  const float4* wp4 = (const float4*)pwt;
  const float4* sp4 = (const float4*)&samp[tp * 512];
  #pragma unroll 8
  for (int c = 0; c < 128; ++c) {
    float4 w4 = wp4[c * 32 + to];
    float4 s4 = sp4[c];
    float wr[4] = {w4.x, w4.y, w4.z, w4.w};
    float sr[4] = {s4.x, s4.y, s4.z, s4.w};
    #pragma unroll
    for (int i = 0; i < 4; ++i)
      #pragma unroll
      for (int j = 0; j < 4; ++j)
        acc[i][j] = fmaf(wr[i], sr[j], acc[i][j]);
  }

  float b0 = pw_b[4 * to + 0], b1 = pw_b[4 * to + 1],
        b2 = pw_b[4 * to + 2], b3 = pw_b[4 * to + 3];
  #pragma unroll
  for (int j = 0; j < 4; ++j) {
    int pix = pixbase + 4 * tp + j;
    float4 v = make_float4(acc[0][j] + b0, acc[1][j] + b1, acc[2][j] + b2, acc[3][j] + b3);
    *(float4*)(s + (size_t)pix * 128 + 4 * to) = v;
  }
}

// ---------------- InstanceNorm stats (per b,c over HW) ----------------
__global__ void k_instats(const float* __restrict__ s, float* __restrict__ ist) {
  int b = blockIdx.x / 36; int tile = blockIdx.x % 36;
  int c = threadIdx.x & 127; int half = threadIdx.x >> 7;
  const float* base = s + (size_t)(b * HW_ + tile * 256) * 128;
  float sum = 0.f, sq = 0.f;
  for (int p = half; p < 256; p += 2) {
    float v = base[p * 128 + c];
    sum += v; sq += v * v;
  }
  __shared__ float r1[256], r2[256];
  r1[threadIdx.x] = sum; r2[threadIdx.x] = sq;
  __syncthreads();
  if (half == 0) {
    atomicAdd(&ist[(b * 128 + c) * 2],     r1[c] + r1[c + 128]);
    atomicAdd(&ist[(b * 128 + c) * 2 + 1], r2[c] + r2[c + 128]);
  }
}

// ---------------- IN finalize: mean/rstd planes ----------------
__global__ void k_infin(const float* __restrict__ ist, float* __restrict__ ifm,
                        float* __restrict__ ifr) {
  int i = blockIdx.x * 256 + threadIdx.x;
  if (i >= 512) return;
  float mean = ist[2 * i] * (1.f / 9216.f);
  float var  = ist[2 * i + 1] * (1.f / 9216.f) - mean * mean;
  ifm[i] = mean;
  ifr[i] = rsqrtf(var + 1e-5f);
}

// ---------------- normalize s -> bf16 MFMA B-frag layout (global) ----------
// nsamp bfrag8 index = (pixblk*4+kk)*64 + g*16 + lp; pix=pixblk*16+lp,
// c = kk*32+g*8+j. thread = one bfrag8 slot (8 channels of one pixel).
__global__ __launch_bounds__(256) void k_norm(
    const float* __restrict__ s, const float* __restrict__ ifm,
    const float* __restrict__ ifr, short* __restrict__ nsamp) {
  int t = blockIdx.x * 256 + threadIdx.x;   // t < NPIX*16
  int lp = t & 15, g = (t >> 4) & 3, kk = (t >> 6) & 3, blk = t >> 8;
  int pix = blk * 16 + lp;
  int c0 = kk * 32 + g * 8;
  int b = pix / HW_;
  const float* sp = s + (size_t)pix * 128 + c0;
  float4 a0 = *(const float4*)sp, a1 = *(const float4*)(sp + 4);
  float4 m0 = *(const float4*)(ifm + b * 128 + c0), m1 = *(const float4*)(ifm + b * 128 + c0 + 4);
  float4 r0 = *(const float4*)(ifr + b * 128 + c0), r1 = *(const float4*)(ifr + b * 128 + c0 + 4);
  bfrag8 o;
  o[0] = f2bf(fmaxf((a0.x - m0.x) * r0.x, 0.f));
  o[1] = f2bf(fmaxf((a0.y - m0.y) * r0.y, 0.f));
  o[2] = f2bf(fmaxf((a0.z - m0.z) * r0.z, 0.f));
  o[3] = f2bf(fmaxf((a0.w - m0.w) * r0.w, 0.f));
  o[4] = f2bf(fmaxf((a1.x - m1.x) * r1.x, 0.f));
  o[5] = f2bf(fmaxf((a1.y - m1.y) * r1.y, 0.f));
  o[6] = f2bf(fmaxf((a1.z - m1.z) * r1.z, 0.f));
  o[7] = f2bf(fmaxf((a1.w - m1.w) * r1.w, 0.f));
  *(bfrag8*)(nsamp + (size_t)t * 8) = o;
}

// ---------------- offset conv as MFMA GEMM with shifted fragments ----------
// off[oc][pix] = bias + sum_{k,c} off_w[oc][c][k] * nsamp[c][pix + dy*96+dx].
// Shift is uniform -> B-frag = frag load at shifted per-lane pixel, with
// per-lane zeroing at image borders. wave = 32 oc x 32 pix; block 4 waves.
__global__ __launch_bounds__(256) void k_offgemm(
    const short* __restrict__ nsamp, const short* __restrict__ wob,
    const float* __restrict__ off_b, float* __restrict__ off) {
  int tid = threadIdx.x;
  int lane = tid & 63, wv = tid >> 6;
  int p0 = blockIdx.x * 128 + wv * 32;
  int lp = lane & 15, g = lane >> 4;
  const bfrag8* np = (const bfrag8*)nsamp;
  const bfrag8* wp = (const bfrag8*)wob;

  f32x4 acc[2][2];   // [mt][nf]
  #pragma unroll
  for (int m = 0; m < 2; ++m)
    #pragma unroll
    for (int n = 0; n < 2; ++n) acc[m][n] = (f32x4){0.f, 0.f, 0.f, 0.f};

  int pn0 = p0 + lp, pn1 = p0 + 16 + lp;
  int x0_ = pn0 % 96, y0_ = (pn0 % HW_) / 96;
  int x1_ = pn1 % 96, y1_ = (pn1 % HW_) / 96;
  const bfrag8 zf = {0, 0, 0, 0, 0, 0, 0, 0};

  for (int k = 0; k < 9; ++k) {
    int dy = k / 3 - 1, dx = k % 3 - 1;
    int sh = dy * 96 + dx;
    bool v0 = ((unsigned)(x0_ + dx) < 96u) && ((unsigned)(y0_ + dy) < 96u);
    bool v1 = ((unsigned)(x1_ + dx) < 96u) && ((unsigned)(y1_ + dy) < 96u);
    int q0 = min(max(pn0 + sh, 0), NPIX - 1);
    int q1 = min(max(pn1 + sh, 0), NPIX - 1);
    size_t a0 = (size_t)(q0 >> 4) * 256 + g * 16 + (q0 & 15);
    size_t a1 = (size_t)(q1 >> 4) * 256 + g * 16 + (q1 & 15);
    #pragma unroll
    for (int kk = 0; kk < 4; ++kk) {
      bfrag8 B0 = np[a0 + kk * 64]; B0 = v0 ? B0 : zf;
      bfrag8 B1 = np[a1 + kk * 64]; B1 = v1 ? B1 : zf;
      bfrag8 A0 = wp[((size_t)(k * 2 + 0) * 4 + kk) * 64 + lane];
      bfrag8 A1 = wp[((size_t)(k * 2 + 1) * 4 + kk) * 64 + lane];
      acc[0][0] = __builtin_amdgcn_mfma_f32_16x16x32_bf16(A0, B0, acc[0][0], 0, 0, 0);
      acc[0][1] = __builtin_amdgcn_mfma_f32_16x16x32_bf16(A0, B1, acc[0][1], 0, 0, 0);
      acc[1][0] = __builtin_amdgcn_mfma_f32_16x16x32_bf16(A1, B0, acc[1][0], 0, 0, 0);
      acc[1][1] = __builtin_amdgcn_mfma_f32_16x16x32_bf16(A1, B1, acc[1][1], 0, 0, 0);
    }
  }

  // D: lane l, reg r -> oc = mt*16 + g*4 + r, pix = p0 + nf*16 + lp
  #pragma unroll
  for (int mt = 0; mt < 2; ++mt) {
    #pragma unroll
    for (int r = 0; r < 4; ++r) {
      int oc = mt * 16 + g * 4 + r;
      if (oc < 18) {
        float bb = off_b[oc];
        off[(size_t)oc * NPIX + p0 + lp]      = acc[mt][0][r] + bb;
        off[(size_t)oc * NPIX + p0 + 16 + lp] = acc[mt][1][r] + bb;
      }
    }
  }
}

// ---------------- deform sampling: bilinear on pre-normalized bf16 ---------
// thread = (pixel, slot-pair); grid (PIX_CHUNK/32, 9). 8 lanes per pixel,
// each thread handles 2 of 16 (kk,g) slots (8 ch each). Corners read from
// nsamp (already relu-normalized, frag layout); output samp frag layout.
__global__ __launch_bounds__(256) void k_sample(
    const short* __restrict__ nsamp, const float* __restrict__ off,
    short* __restrict__ samp, int p0) {
  int k  = blockIdx.y;
  int tid = threadIdx.x;
  int pw_ = tid >> 3;        // pixel 0..31
  int l8  = tid & 7;         // slot low bits
  int pl = blockIdx.x * 32 + pw_;
  int pix = p0 + pl;
  int b = pix / HW_; int hw = pix % HW_; int y = hw / 96; int x = hw % 96;

  float dy = off[(size_t)(2 * k)     * NPIX + pix];
  float dx = off[(size_t)(2 * k + 1) * NPIX + pix];
  float py = (float)y + (float)(k / 3 - 1) + dy;
  float px = (float)x + (float)(k % 3 - 1) + dx;
  float y0f = floorf(py), x0f = floorf(px);
  float ly = py - y0f, lx = px - x0f;
  int y0 = (int)y0f, x0 = (int)x0f;
  bool vy0 = (y0 >= 0) && (y0 < 96), vy1 = (y0 + 1 >= 0) && (y0 + 1 < 96);
  bool vx0 = (x0 >= 0) && (x0 < 96), vx1 = (x0 + 1 >= 0) && (x0 + 1 < 96);
  float w00 = (vy0 && vx0) ? (1.f - ly) * (1.f - lx) : 0.f;
  float w01 = (vy0 && vx1) ? (1.f - ly) * lx : 0.f;
  float w10 = (vy1 && vx0) ? ly * (1.f - lx) : 0.f;
  float w11 = (vy1 && vx1) ? ly * lx : 0.f;
  int yc0 = min(max(y0, 0), 95), yc1 = min(max(y0 + 1, 0), 95);
  int xc0 = min(max(x0, 0), 95), xc1 = min(max(x0 + 1, 0), 95);
  int qb = b * HW_;
  int q00 = qb + yc0 * 96 + xc0, q01 = qb + yc0 * 96 + xc1;
  int q10 = qb + yc1 * 96 + xc0, q11 = qb + yc1 * 96 + xc1;
  const bfrag8* np = (const bfrag8*)nsamp;

  int pixblk = pl >> 4, lp = pl & 15;
  bfrag8* sp8 = (bfrag8*)samp;

  #pragma unroll
  for (int it = 0; it < 2; ++it) {
    int slot = l8 + it * 8;
    int kk = slot >> 2, g = slot & 3;
    int so = kk * 64 + g * 16;
    bfrag8 cA = np[(size_t)(q00 >> 4) * 256 + so + (q00 & 15)];
    bfrag8 cB = np[(size_t)(q01 >> 4) * 256 + so + (q01 & 15)];
    bfrag8 cC = np[(size_t)(q10 >> 4) * 256 + so + (q10 & 15)];
    bfrag8 cD = np[(size_t)(q11 >> 4) * 256 + so + (q11 & 15)];
    bfrag8 o;
    #pragma unroll
    for (int j = 0; j < 8; ++j) {
      float v = bf2f(cA[j]) * w00 + bf2f(cB[j]) * w01
              + bf2f(cC[j]) * w10 + bf2f(cD[j]) * w11;
      o[j] = f2bf(v);
    }
    sp8[((size_t)pixblk * 36 + k * 4 + kk) * 64 + g * 16 + lp] = o;
  }
}

// ---------------- deform GEMM: D[oc][pix] = sum_K W*samp, bf16 MFMA ----------
// block = 128 oc x 64 pix, 4 waves; wave = 64 oc (4 mt) x 32 pix (2 pixblk).
// Epilogue fuses bias + GroupNorm partial sums.
__global__ __launch_bounds__(256) void k_degemm(
    const short* __restrict__ samp, const short* __restrict__ wtb,
    const float* __restrict__ de_b, float* __restrict__ d,
    float* __restrict__ gst, int p0) {
  int tid = threadIdx.x;
  int lane = tid & 63, wv = tid >> 6;
  int pixblk = blockIdx.x * 4 + (wv & 1) * 2;
  int mtg0 = (wv >> 1) * 4;
  const bfrag8* sp = (const bfrag8*)samp;
  const bfrag8* wp = (const bfrag8*)wtb;

  f32x4 acc[4][2];
  #pragma unroll
  for (int m = 0; m < 4; ++m)
    #pragma unroll
    for (int n = 0; n < 2; ++n) acc[m][n] = (f32x4){0.f, 0.f, 0.f, 0.f};

  #pragma unroll 4
  for (int ks = 0; ks < 36; ++ks) {
    bfrag8 bf0 = sp[((size_t)(pixblk + 0) * 36 + ks) * 64 + lane];
    bfrag8 bf1 = sp[((size_t)(pixblk + 1) * 36 + ks) * 64 + lane];
    int k = ks >> 2, kk = ks & 3;
    #pragma unroll
    for (int m = 0; m < 4; ++m) {
      bfrag8 af = wp[((size_t)((k * 8 + mtg0 + m) * 4 + kk)) * 64 + lane];
      acc[m][0] = __builtin_amdgcn_mfma_f32_16x16x32_bf16(af, bf0, acc[m][0], 0, 0, 0);
      acc[m][1] = __builtin_amdgcn_mfma_f32_16x16x32_bf16(af, bf1, acc[m][1], 0, 0, 0);
    }
  }

  int g = lane >> 4, lp = lane & 15;
  float lsum = 0.f, lsq = 0.f;
  #pragma unroll
  for (int m = 0; m < 4; ++m) {
    int oc = (mtg0 + m) * 16 + g * 4;
    float4 bias = *(const float4*)(de_b + oc);
    #pragma unroll
    for (int n = 0; n < 2; ++n) {
      int pix = p0 + (pixblk + n) * 16 + lp;
      f32x4 a = acc[m][n];
      float4 v = make_float4(a[0] + bias.x, a[1] + bias.y, a[2] + bias.z, a[3] + bias.w);
      *(float4*)(d + (size_t)pix * 128 + oc) = v;
      lsum += v.x + v.y + v.z + v.w;
      lsq  += v.x * v.x + v.y * v.y + v.z * v.z + v.w * v.w;
    }
  }
  __shared__ float r1[256], r2[256];
  r1[tid] = lsum; r2[tid] = lsq;
  __syncthreads();
  for (int st = 128; st > 0; st >>= 1) {
    if (tid < st) { r1[tid] += r1[tid + st]; r2[tid] += r2[tid + st]; }
    __syncthreads();
  }
  if (tid == 0) {
    int b = (p0 + blockIdx.x * 64) / HW_;
    atomicAdd(&gst[b * 2],     r1[0]);
    atomicAdd(&gst[b * 2 + 1], r2[0]);
  }
}

__global__ void k_gnfin(const float* __restrict__ gst, float* __restrict__ gfin) {
  int b = threadIdx.x;
  if (b >= 4) return;
  const float invN = 1.f / (float)BATCH_STRIDE;
  float mean = gst[2 * b] * invN;
  float var  = gst[2 * b + 1] * invN - mean * mean;
  gfin[2 * b] = mean;
  gfin[2 * b + 1] = rsqrtf(var + 1e-5f);
}

// ---------------- final: GN + sigmoid gate + shortcut, LDS transpose --------
__global__ __launch_bounds__(256) void k_final(
    const float* __restrict__ d, const float* __restrict__ s,
    const float* __restrict__ ifm, const float* __restrict__ ifr,
    const float* __restrict__ gfin, const float* __restrict__ gn_w,
    const float* __restrict__ gn_b, float* __restrict__ out) {
  __shared__ float t[128 * 33];
  int tid = threadIdx.x;
  int pixbase = blockIdx.x * 32;
  int b = pixbase / HW_;
  int hw0 = pixbase % HW_;
  float gm = gfin[2 * b], gr = gfin[2 * b + 1];

  int px0 = tid >> 3;
  int c0  = (tid & 7) * 16;
  const float* dp = d + ((size_t)(pixbase + px0)) * 128;
  const float* sp = s + ((size_t)(pixbase + px0)) * 128;
  #pragma unroll
  for (int q = 0; q < 4; ++q) {
    int c = c0 + q * 4;
    float4 dv = *(const float4*)(dp + c);
    float4 sv = *(const float4*)(sp + c);
    float4 m4 = *(const float4*)(ifm + b * 128 + c);
    float4 r4 = *(const float4*)(ifr + b * 128 + c);
    float4 w4 = *(const float4*)(gn_w + c);
    float4 b4 = *(const float4*)(gn_b + c);
    float svn, dn, gg;
    svn = fmaxf((sv.x - m4.x) * r4.x, 0.f);
    dn  = (dv.x - gm) * gr * w4.x + b4.x;
    gg  = 1.f / (1.f + expf(-dn));
    t[(c + 0) * 33 + px0] = svn * (1.f + gg);
    svn = fmaxf((sv.y - m4.y) * r4.y, 0.f);
    dn  = (dv.y - gm) * gr * w4.y + b4.y;
    gg  = 1.f / (1.f + expf(-dn));
    t[(c + 1) * 33 + px0] = svn * (1.f + gg);
    svn = fmaxf((sv.z - m4.z) * r4.z, 0.f);
    dn  = (dv.z - gm) * gr * w4.z + b4.z;
    gg  = 1.f / (1.f + expf(-dn));
    t[(c + 2) * 33 + px0] = svn * (1.f + gg);
    svn = fmaxf((sv.w - m4.w) * r4.w, 0.f);
    dn  = (dv.w - gm) * gr * w4.w + b4.w;
    gg  = 1.f / (1.f + expf(-dn));
    t[(c + 3) * 33 + px0] = svn * (1.f + gg);
  }
  __syncthreads();
  if (tid < 128) {
    float* op = out + (size_t)(b * 128 + tid) * HW_ + hw0;
    #pragma unroll
    for (int p4 = 0; p4 < 8; ++p4) {
      float4 v = make_float4(t[tid * 33 + p4 * 4], t[tid * 33 + p4 * 4 + 1],
                             t[tid * 33 + p4 * 4 + 2], t[tid * 33 + p4 * 4 + 3]);
      *(float4*)(op + p4 * 4) = v;
    }
  }
}

extern "C" void kernel_launch(void* const* d_in, const int* in_sizes, int n_in,
                              void* d_out, int out_size, void* d_ws, size_t ws_size,
                              hipStream_t stream) {
  (void)in_sizes; (void)n_in; (void)out_size; (void)ws_size;
  const float* x     = (const float*)d_in[0];
  const float* dw_w  = (const float*)d_in[1];
  const float* dw_b  = (const float*)d_in[2];
  const float* pw_w  = (const float*)d_in[3];
  const float* pw_b  = (const float*)d_in[4];
  const float* off_w = (const float*)d_in[5];
  const float* off_b = (const float*)d_in[6];
  const float* de_w  = (const float*)d_in[7];
  const float* de_b  = (const float*)d_in[8];
  const float* gn_w  = (const float*)d_in[9];
  const float* gn_b  = (const float*)d_in[10];
  float* out = (float*)d_out;

  float* ws   = (float*)d_ws;
  float* h1   = ws;                 // NCHW depthwise out; reused as deform out d (BHWC)
  float* s    = h1 + BHWC;          // BHWC raw pw output (normalized on the fly)
  float* off  = s + BHWC;           // [18][NPIX] offsets (oc-major)
  short* wtb  = (short*)(off + NPIX * 18);  // bf16 A-frag de_w (147456 shorts)
  short* wob  = wtb + 147456;       // bf16 A-frag off_w (36864 shorts)
  float* pwt  = (float*)(wob + 36864);  // [c][oc] 16384
  float* ist  = pwt + 16384;        // [B][C][2] sum,sumsq
  float* ifm  = ist + 1024;         // [B][C] mean
  float* ifr  = ifm + 512;          // [B][C] rstd
  float* gst  = ifr + 512;          // [B][2]
  float* gfin = gst + 8;            // [B][2]
  short* nsamp = (short*)(gfin + 8);        // bf16 normalized s, frag layout (NPIX*128)
  short* samp = nsamp + (size_t)NPIX * 128; // bf16 deformed samples (PIX_CHUNK*1152)

  hipMemsetAsync(ist, 0, (1024 + 512 + 512 + 8 + 8) * sizeof(float), stream);

  k_transpose_w<<<576, 256, 0, stream>>>(de_w, off_w, pw_w, wtb, wob, pwt);
  k_dw<<<BHWC / 256, 256, 0, stream>>>(x, dw_w, dw_b, h1);
  k_pw<<<NPIX / 32, 256, 0, stream>>>(h1, pwt, pw_b, s);
  k_instats<<<4 * 36, 256, 0, stream>>>(s, ist);
  k_infin<<<2, 256, 0, stream>>>(ist, ifm, ifr);
  k_norm<<<NPIX * 16 / 256, 256, 0, stream>>>(s, ifm, ifr, nsamp);
  k_offgemm<<<NPIX / 128, 256, 0, stream>>>(nsamp, wob, off_b, off);

  dim3 sgrid(PIX_CHUNK / 32, 9);
  for (int chunk = 0; chunk < 2; ++chunk) {
    int p0 = chunk * PIX_CHUNK;
    k_sample<<<sgrid, 256, 0, stream>>>(nsamp, off, samp, p0);
    k_degemm<<<PIX_CHUNK / 64, 256, 0, stream>>>(samp, wtb, de_b, h1, gst, p0);
  }

  k_gnfin<<<1, 64, 0, stream>>>(gst, gfin);
  k_final<<<NPIX / 32, 256, 0, stream>>>(h1, s, ifm, ifr, gfin, gn_w, gn_b, out);
}

// Round 9
// 230.777 us; speedup vs baseline: 3.1809x; 1.2546x over previous
//
#include <hip/hip_runtime.h>
#include <hip/hip_bf16.h>
#include <math.h>

#define B_    4
#define C_    128
#define H_    96
#define W_    96
#define HW_   9216          // H*W
#define NPIX  36864         // B*HW
#define BHWC  4718592       // B*HW*C
#define BATCH_STRIDE 1179648 // HW*C

typedef __attribute__((ext_vector_type(8))) short bfrag8;
typedef __attribute__((ext_vector_type(4))) float f32x4;

static __device__ __forceinline__ short f2bf(float f) {
  __hip_bfloat16 h = __float2bfloat16(f);
  short s;
  __builtin_memcpy(&s, &h, 2);
  return s;
}
static __device__ __forceinline__ float bf2f(short s) {
  unsigned u = ((unsigned)(unsigned short)s) << 16;
  float f;
  __builtin_memcpy(&f, &u, 4);
  return f;
}

// ---------------- weight transposes ----------------
// wtb: bf16 A-frag order [k][mt(8)][kk(4)][lane(64)][j(8)] for de_w (147456)
// wob: bf16 A-frag order [k][mt(2)][kk(4)][lane(64)][j(8)] for off_w (36864)
// pwt: [c][oc] from pw_w [oc][c] (16384)
__global__ void k_transpose_w(const float* __restrict__ de_w,
                              const float* __restrict__ off_w,
                              const float* __restrict__ pw_w,
                              short* __restrict__ wtb, short* __restrict__ wob,
                              float* __restrict__ pwt) {
  int i = blockIdx.x * 256 + threadIdx.x;
  if (i < 147456) {
    int j  = i & 7;
    int l  = (i >> 3) & 63;
    int kk = (i >> 9) & 3;
    int mt = (i >> 11) & 7;
    int k  = i >> 14;
    int oc = mt * 16 + (l & 15);
    int c  = kk * 32 + ((l >> 4) << 3) + j;
    wtb[i] = f2bf(de_w[(oc * 128 + c) * 9 + k]);
  }
  if (i < 36864) {
    int j  = i & 7;
    int l  = (i >> 3) & 63;
    int kk = (i >> 9) & 3;
    int mt = (i >> 11) & 1;
    int k  = i >> 12;
    int oc = mt * 16 + (l & 15);
    int c  = kk * 32 + ((l >> 4) << 3) + j;
    wob[i] = (oc < 18) ? f2bf(off_w[(oc * 128 + c) * 9 + k]) : (short)0;
  }
  if (i < 16384) {
    int oc = i & 127; int c = i >> 7;
    pwt[i] = pw_w[oc * 128 + c];
  }
}

// ---------------- depthwise 3x3 + bias : NCHW in -> NCHW out ----------------
__global__ void k_dw(const float* __restrict__ x, const float* __restrict__ dw_w,
                     const float* __restrict__ dw_b, float* __restrict__ h1) {
  int i = blockIdx.x * 256 + threadIdx.x;
  if (i >= BHWC) return;
  int xx = i % 96; int yy = (i / 96) % 96; int c = (i / HW_) % 128; int b = i / BATCH_STRIDE;
  const float* xp = x + (b * 128 + c) * HW_;
  const float* wp = dw_w + c * 9;
  float acc = dw_b[c];
  #pragma unroll
  for (int dy = 0; dy < 3; ++dy) {
    int sy = yy + dy - 1;
    if (sy < 0 || sy >= 96) continue;
    #pragma unroll
    for (int dx = 0; dx < 3; ++dx) {
      int sx = xx + dx - 1;
      if (sx < 0 || sx >= 96) continue;
      acc += xp[sy * 96 + sx] * wp[dy * 3 + dx];
    }
  }
  h1[i] = acc;
}

// ---------------- pointwise 1x1 + bias : NCHW in -> BHWC out ----------------
__global__ __launch_bounds__(256) void k_pw(
    const float* __restrict__ h1, const float* __restrict__ pwt,
    const float* __restrict__ pw_b, float* __restrict__ s) {
  __shared__ float samp[32 * 128];
  int tid = threadIdx.x;
  int pixbase = blockIdx.x * 32;
  int b = pixbase / HW_;
  int hw0 = pixbase % HW_;

  if (tid < 128) {
    const float* hp = h1 + (size_t)(b * 128 + tid) * HW_ + hw0;
    #pragma unroll
    for (int p4 = 0; p4 < 8; ++p4) {
      float4 v = *(const float4*)(hp + p4 * 4);
      *(float4*)&samp[p4 * 512 + tid * 4] = v;
    }
  }
  __syncthreads();

  int to = tid & 31;
  int tp = tid >> 5;
  float acc[4][4];
  #pragma unroll
  for (int i = 0; i < 4; ++i)
    #pragma unroll
    for (int j = 0; j < 4; ++j) acc[i][j] = 0.f;

  const float4* wp4 = (const float4*)pwt;
  const float4* sp4 = (const float4*)&samp[tp * 512];
  #pragma unroll 8
  for (int c = 0; c < 128; ++c) {
    float4 w4 = wp4[c * 32 + to];
    float4 s4 = sp4[c];
    float wr[4] = {w4.x, w4.y, w4.z, w4.w};
    float sr[4] = {s4.x, s4.y, s4.z, s4.w};
    #pragma unroll
    for (int i = 0; i < 4; ++i)
      #pragma unroll
      for (int j = 0; j < 4; ++j)
        acc[i][j] = fmaf(wr[i], sr[j], acc[i][j]);
  }

  float b0 = pw_b[4 * to + 0], b1 = pw_b[4 * to + 1],
        b2 = pw_b[4 * to + 2], b3 = pw_b[4 * to + 3];
  #pragma unroll
  for (int j = 0; j < 4; ++j) {
    int pix = pixbase + 4 * tp + j;
    float4 v = make_float4(acc[0][j] + b0, acc[1][j] + b1, acc[2][j] + b2, acc[3][j] + b3);
    *(float4*)(s + (size_t)pix * 128 + 4 * to) = v;
  }
}

// ---------------- InstanceNorm stats (per b,c over HW) ----------------
__global__ void k_instats(const float* __restrict__ s, float* __restrict__ ist) {
  int b = blockIdx.x / 36; int tile = blockIdx.x % 36;
  int c = threadIdx.x & 127; int half = threadIdx.x >> 7;
  const float* base = s + (size_t)(b * HW_ + tile * 256) * 128;
  float sum = 0.f, sq = 0.f;
  for (int p = half; p < 256; p += 2) {
    float v = base[p * 128 + c];
    sum += v; sq += v * v;
  }
  __shared__ float r1[256], r2[256];
  r1[threadIdx.x] = sum; r2[threadIdx.x] = sq;
  __syncthreads();
  if (half == 0) {
    atomicAdd(&ist[(b * 128 + c) * 2],     r1[c] + r1[c + 128]);
    atomicAdd(&ist[(b * 128 + c) * 2 + 1], r2[c] + r2[c + 128]);
  }
}

__global__ void k_infin(const float* __restrict__ ist, float* __restrict__ ifm,
                        float* __restrict__ ifr) {
  int i = blockIdx.x * 256 + threadIdx.x;
  if (i >= 512) return;
  float mean = ist[2 * i] * (1.f / 9216.f);
  float var  = ist[2 * i + 1] * (1.f / 9216.f) - mean * mean;
  ifm[i] = mean;
  ifr[i] = rsqrtf(var + 1e-5f);
}

// ---------------- normalize s -> bf16 MFMA B-frag layout (global) ----------
__global__ __launch_bounds__(256) void k_norm(
    const float* __restrict__ s, const float* __restrict__ ifm,
    const float* __restrict__ ifr, short* __restrict__ nsamp) {
  int t = blockIdx.x * 256 + threadIdx.x;   // t < NPIX*16
  int lp = t & 15, g = (t >> 4) & 3, kk = (t >> 6) & 3, blk = t >> 8;
  int pix = blk * 16 + lp;
  int c0 = kk * 32 + g * 8;
  int b = pix / HW_;
  const float* sp = s + (size_t)pix * 128 + c0;
  float4 a0 = *(const float4*)sp, a1 = *(const float4*)(sp + 4);
  float4 m0 = *(const float4*)(ifm + b * 128 + c0), m1 = *(const float4*)(ifm + b * 128 + c0 + 4);
  float4 r0 = *(const float4*)(ifr + b * 128 + c0), r1 = *(const float4*)(ifr + b * 128 + c0 + 4);
  bfrag8 o;
  o[0] = f2bf(fmaxf((a0.x - m0.x) * r0.x, 0.f));
  o[1] = f2bf(fmaxf((a0.y - m0.y) * r0.y, 0.f));
  o[2] = f2bf(fmaxf((a0.z - m0.z) * r0.z, 0.f));
  o[3] = f2bf(fmaxf((a0.w - m0.w) * r0.w, 0.f));
  o[4] = f2bf(fmaxf((a1.x - m1.x) * r1.x, 0.f));
  o[5] = f2bf(fmaxf((a1.y - m1.y) * r1.y, 0.f));
  o[6] = f2bf(fmaxf((a1.z - m1.z) * r1.z, 0.f));
  o[7] = f2bf(fmaxf((a1.w - m1.w) * r1.w, 0.f));
  *(bfrag8*)(nsamp + (size_t)t * 8) = o;
}

// ---------------- offset conv as MFMA GEMM with shifted fragments ----------
__global__ __launch_bounds__(256) void k_offgemm(
    const short* __restrict__ nsamp, const short* __restrict__ wob,
    const float* __restrict__ off_b, float* __restrict__ off) {
  int tid = threadIdx.x;
  int lane = tid & 63, wv = tid >> 6;
  int p0 = blockIdx.x * 128 + wv * 32;
  int lp = lane & 15, g = lane >> 4;
  const bfrag8* np = (const bfrag8*)nsamp;
  const bfrag8* wp = (const bfrag8*)wob;

  f32x4 acc[2][2];
  #pragma unroll
  for (int m = 0; m < 2; ++m)
    #pragma unroll
    for (int n = 0; n < 2; ++n) acc[m][n] = (f32x4){0.f, 0.f, 0.f, 0.f};

  int pn0 = p0 + lp, pn1 = p0 + 16 + lp;
  int x0_ = pn0 % 96, y0_ = (pn0 % HW_) / 96;
  int x1_ = pn1 % 96, y1_ = (pn1 % HW_) / 96;
  const bfrag8 zf = {0, 0, 0, 0, 0, 0, 0, 0};

  for (int k = 0; k < 9; ++k) {
    int dy = k / 3 - 1, dx = k % 3 - 1;
    int sh = dy * 96 + dx;
    bool v0 = ((unsigned)(x0_ + dx) < 96u) && ((unsigned)(y0_ + dy) < 96u);
    bool v1 = ((unsigned)(x1_ + dx) < 96u) && ((unsigned)(y1_ + dy) < 96u);
    int q0 = min(max(pn0 + sh, 0), NPIX - 1);
    int q1 = min(max(pn1 + sh, 0), NPIX - 1);
    size_t a0 = (size_t)(q0 >> 4) * 256 + g * 16 + (q0 & 15);
    size_t a1 = (size_t)(q1 >> 4) * 256 + g * 16 + (q1 & 15);
    #pragma unroll
    for (int kk = 0; kk < 4; ++kk) {
      bfrag8 B0 = np[a0 + kk * 64]; B0 = v0 ? B0 : zf;
      bfrag8 B1 = np[a1 + kk * 64]; B1 = v1 ? B1 : zf;
      bfrag8 A0 = wp[((size_t)(k * 2 + 0) * 4 + kk) * 64 + lane];
      bfrag8 A1 = wp[((size_t)(k * 2 + 1) * 4 + kk) * 64 + lane];
      acc[0][0] = __builtin_amdgcn_mfma_f32_16x16x32_bf16(A0, B0, acc[0][0], 0, 0, 0);
      acc[0][1] = __builtin_amdgcn_mfma_f32_16x16x32_bf16(A0, B1, acc[0][1], 0, 0, 0);
      acc[1][0] = __builtin_amdgcn_mfma_f32_16x16x32_bf16(A1, B0, acc[1][0], 0, 0, 0);
      acc[1][1] = __builtin_amdgcn_mfma_f32_16x16x32_bf16(A1, B1, acc[1][1], 0, 0, 0);
    }
  }

  #pragma unroll
  for (int mt = 0; mt < 2; ++mt) {
    #pragma unroll
    for (int r = 0; r < 4; ++r) {
      int oc = mt * 16 + g * 4 + r;
      if (oc < 18) {
        float bb = off_b[oc];
        off[(size_t)oc * NPIX + p0 + lp]      = acc[mt][0][r] + bb;
        off[(size_t)oc * NPIX + p0 + 16 + lp] = acc[mt][1][r] + bb;
      }
    }
  }
}

// ---------------- fused deform: sample->LDS (dbuf) + MFMA + GN stats --------
// block = 64 pix x 128 oc, 4 waves; wave = 4 mt x 2 pixblk.
// Per tap: sample tap k+1 into LDS buf^1 while MFMA consumes buf (1 barrier/tap).
__global__ __launch_bounds__(256) void k_deform_f(
    const short* __restrict__ nsamp, const float* __restrict__ off,
    const short* __restrict__ wtb, const float* __restrict__ de_b,
    float* __restrict__ d, float* __restrict__ gst) {
  __shared__ short lbuf[2][4][4][64][8];   // [buf][pixblk][kk][lane][j], 32 KB
  __shared__ float r1[256], r2[256];
  int tid = threadIdx.x;
  int pixbase = blockIdx.x * 64;

  // --- sampling mapping: 4 threads per pixel, 4 (kk=it, g=l4) slots each ---
  int pw_ = tid >> 2;            // pixel 0..63
  int l4  = tid & 3;             // g
  int pix_s = pixbase + pw_;
  int hw_s = pix_s % HW_;
  int ys = hw_s / 96, xs = hw_s % 96;
  int qb = (pix_s / HW_) * HW_;
  int pb_s = pw_ >> 4, lp_s = pw_ & 15;
  const bfrag8* np = (const bfrag8*)nsamp;

  // --- MFMA mapping ---
  int lane = tid & 63, wv = tid >> 6;
  int mtg0 = (wv & 1) * 4;
  int pb0 = (wv >> 1) * 2;
  const bfrag8* wp = (const bfrag8*)wtb;

  f32x4 acc[4][2];
  #pragma unroll
  for (int m = 0; m < 4; ++m)
    #pragma unroll
    for (int n = 0; n < 2; ++n) acc[m][n] = (f32x4){0.f, 0.f, 0.f, 0.f};

  auto SAMPLE = [&](int k, int buf) {
    float dy = off[(size_t)(2 * k)     * NPIX + pix_s];
    float dx = off[(size_t)(2 * k + 1) * NPIX + pix_s];
    float py = (float)ys + (float)(k / 3 - 1) + dy;
    float px = (float)xs + (float)(k % 3 - 1) + dx;
    float y0f = floorf(py), x0f = floorf(px);
    float ly = py - y0f, lx = px - x0f;
    int y0 = (int)y0f, x0 = (int)x0f;
    bool vy0 = (y0 >= 0) && (y0 < 96), vy1 = (y0 + 1 >= 0) && (y0 + 1 < 96);
    bool vx0 = (x0 >= 0) && (x0 < 96), vx1 = (x0 + 1 >= 0) && (x0 + 1 < 96);
    float w00 = (vy0 && vx0) ? (1.f - ly) * (1.f - lx) : 0.f;
    float w01 = (vy0 && vx1) ? (1.f - ly) * lx : 0.f;
    float w10 = (vy1 && vx0) ? ly * (1.f - lx) : 0.f;
    float w11 = (vy1 && vx1) ? ly * lx : 0.f;
    int yc0 = min(max(y0, 0), 95), yc1 = min(max(y0 + 1, 0), 95);
    int xc0 = min(max(x0, 0), 95), xc1 = min(max(x0 + 1, 0), 95);
    int q00 = qb + yc0 * 96 + xc0, q01 = qb + yc0 * 96 + xc1;
    int q10 = qb + yc1 * 96 + xc0, q11 = qb + yc1 * 96 + xc1;
    size_t b00 = (size_t)(q00 >> 4) * 256 + l4 * 16 + (q00 & 15);
    size_t b01 = (size_t)(q01 >> 4) * 256 + l4 * 16 + (q01 & 15);
    size_t b10 = (size_t)(q10 >> 4) * 256 + l4 * 16 + (q10 & 15);
    size_t b11 = (size_t)(q11 >> 4) * 256 + l4 * 16 + (q11 & 15);
    #pragma unroll
    for (int kk = 0; kk < 4; ++kk) {
      bfrag8 cA = np[b00 + kk * 64];
      bfrag8 cB = np[b01 + kk * 64];
      bfrag8 cC = np[b10 + kk * 64];
      bfrag8 cD = np[b11 + kk * 64];
      bfrag8 o;
      #pragma unroll
      for (int j = 0; j < 8; ++j) {
        float v = bf2f(cA[j]) * w00 + bf2f(cB[j]) * w01
                + bf2f(cC[j]) * w10 + bf2f(cD[j]) * w11;
        o[j] = f2bf(v);
      }
      *(bfrag8*)&lbuf[buf][pb_s][kk][l4 * 16 + lp_s][0] = o;
    }
  };

  SAMPLE(0, 0);
  __syncthreads();
  for (int k = 0; k < 9; ++k) {
    int cur = k & 1;
    if (k < 8) SAMPLE(k + 1, cur ^ 1);
    #pragma unroll
    for (int kk = 0; kk < 4; ++kk) {
      bfrag8 B0 = *(const bfrag8*)&lbuf[cur][pb0 + 0][kk][lane][0];
      bfrag8 B1 = *(const bfrag8*)&lbuf[cur][pb0 + 1][kk][lane][0];
      #pragma unroll
      for (int m = 0; m < 4; ++m) {
        bfrag8 af = wp[((size_t)((k * 8 + mtg0 + m) * 4 + kk)) * 64 + lane];
        acc[m][0] = __builtin_amdgcn_mfma_f32_16x16x32_bf16(af, B0, acc[m][0], 0, 0, 0);
        acc[m][1] = __builtin_amdgcn_mfma_f32_16x16x32_bf16(af, B1, acc[m][1], 0, 0, 0);
      }
    }
    __syncthreads();
  }

  // epilogue: bias + store + GN partials. D: lane l reg r -> oc_local=(l>>4)*4+r, pix=l&15
  int g = lane >> 4, lp = lane & 15;
  float lsum = 0.f, lsq = 0.f;
  #pragma unroll
  for (int m = 0; m < 4; ++m) {
    int oc = (mtg0 + m) * 16 + g * 4;
    float4 bias = *(const float4*)(de_b + oc);
    #pragma unroll
    for (int n = 0; n < 2; ++n) {
      int pix = pixbase + (pb0 + n) * 16 + lp;
      f32x4 a = acc[m][n];
      float4 v = make_float4(a[0] + bias.x, a[1] + bias.y, a[2] + bias.z, a[3] + bias.w);
      *(float4*)(d + (size_t)pix * 128 + oc) = v;
      lsum += v.x + v.y + v.z + v.w;
      lsq  += v.x * v.x + v.y * v.y + v.z * v.z + v.w * v.w;
    }
  }
  r1[tid] = lsum; r2[tid] = lsq;
  __syncthreads();
  for (int st = 128; st > 0; st >>= 1) {
    if (tid < st) { r1[tid] += r1[tid + st]; r2[tid] += r2[tid + st]; }
    __syncthreads();
  }
  if (tid == 0) {
    int b = pixbase / HW_;
    atomicAdd(&gst[b * 2],     r1[0]);
    atomicAdd(&gst[b * 2 + 1], r2[0]);
  }
}

__global__ void k_gnfin(const float* __restrict__ gst, float* __restrict__ gfin) {
  int b = threadIdx.x;
  if (b >= 4) return;
  const float invN = 1.f / (float)BATCH_STRIDE;
  float mean = gst[2 * b] * invN;
  float var  = gst[2 * b + 1] * invN - mean * mean;
  gfin[2 * b] = mean;
  gfin[2 * b + 1] = rsqrtf(var + 1e-5f);
}

// ---------------- final: GN + sigmoid gate + shortcut, LDS transpose --------
__global__ __launch_bounds__(256) void k_final(
    const float* __restrict__ d, const float* __restrict__ s,
    const float* __restrict__ ifm, const float* __restrict__ ifr,
    const float* __restrict__ gfin, const float* __restrict__ gn_w,
    const float* __restrict__ gn_b, float* __restrict__ out) {
  __shared__ float t[128 * 33];
  int tid = threadIdx.x;
  int pixbase = blockIdx.x * 32;
  int b = pixbase / HW_;
  int hw0 = pixbase % HW_;
  float gm = gfin[2 * b], gr = gfin[2 * b + 1];

  int px0 = tid >> 3;
  int c0  = (tid & 7) * 16;
  const float* dp = d + ((size_t)(pixbase + px0)) * 128;
  const float* sp = s + ((size_t)(pixbase + px0)) * 128;
  #pragma unroll
  for (int q = 0; q < 4; ++q) {
    int c = c0 + q * 4;
    float4 dv = *(const float4*)(dp + c);
    float4 sv = *(const float4*)(sp + c);
    float4 m4 = *(const float4*)(ifm + b * 128 + c);
    float4 r4 = *(const float4*)(ifr + b * 128 + c);
    float4 w4 = *(const float4*)(gn_w + c);
    float4 b4 = *(const float4*)(gn_b + c);
    float svn, dn, gg;
    svn = fmaxf((sv.x - m4.x) * r4.x, 0.f);
    dn  = (dv.x - gm) * gr * w4.x + b4.x;
    gg  = 1.f / (1.f + expf(-dn));
    t[(c + 0) * 33 + px0] = svn * (1.f + gg);
    svn = fmaxf((sv.y - m4.y) * r4.y, 0.f);
    dn  = (dv.y - gm) * gr * w4.y + b4.y;
    gg  = 1.f / (1.f + expf(-dn));
    t[(c + 1) * 33 + px0] = svn * (1.f + gg);
    svn = fmaxf((sv.z - m4.z) * r4.z, 0.f);
    dn  = (dv.z - gm) * gr * w4.z + b4.z;
    gg  = 1.f / (1.f + expf(-dn));
    t[(c + 2) * 33 + px0] = svn * (1.f + gg);
    svn = fmaxf((sv.w - m4.w) * r4.w, 0.f);
    dn  = (dv.w - gm) * gr * w4.w + b4.w;
    gg  = 1.f / (1.f + expf(-dn));
    t[(c + 3) * 33 + px0] = svn * (1.f + gg);
  }
  __syncthreads();
  if (tid < 128) {
    float* op = out + (size_t)(b * 128 + tid) * HW_ + hw0;
    #pragma unroll
    for (int p4 = 0; p4 < 8; ++p4) {
      float4 v = make_float4(t[tid * 33 + p4 * 4], t[tid * 33 + p4 * 4 + 1],
                             t[tid * 33 + p4 * 4 + 2], t[tid * 33 + p4 * 4 + 3]);
      *(float4*)(op + p4 * 4) = v;
    }
  }
}

extern "C" void kernel_launch(void* const* d_in, const int* in_sizes, int n_in,
                              void* d_out, int out_size, void* d_ws, size_t ws_size,
                              hipStream_t stream) {
  (void)in_sizes; (void)n_in; (void)out_size; (void)ws_size;
  const float* x     = (const float*)d_in[0];
  const float* dw_w  = (const float*)d_in[1];
  const float* dw_b  = (const float*)d_in[2];
  const float* pw_w  = (const float*)d_in[3];
  const float* pw_b  = (const float*)d_in[4];
  const float* off_w = (const float*)d_in[5];
  const float* off_b = (const float*)d_in[6];
  const float* de_w  = (const float*)d_in[7];
  const float* de_b  = (const float*)d_in[8];
  const float* gn_w  = (const float*)d_in[9];
  const float* gn_b  = (const float*)d_in[10];
  float* out = (float*)d_out;

  float* ws   = (float*)d_ws;
  float* h1   = ws;                 // NCHW depthwise out; reused as deform out d (BHWC)
  float* s    = h1 + BHWC;          // BHWC raw pw output (normalized on the fly)
  float* off  = s + BHWC;           // [18][NPIX] offsets (oc-major)
  short* wtb  = (short*)(off + NPIX * 18);  // bf16 A-frag de_w (147456 shorts)
  short* wob  = wtb + 147456;       // bf16 A-frag off_w (36864 shorts)
  float* pwt  = (float*)(wob + 36864);  // [c][oc] 16384
  float* ist  = pwt + 16384;        // [B][C][2] sum,sumsq
  float* ifm  = ist + 1024;         // [B][C] mean
  float* ifr  = ifm + 512;          // [B][C] rstd
  float* gst  = ifr + 512;          // [B][2]
  float* gfin = gst + 8;            // [B][2]
  short* nsamp = (short*)(gfin + 8);        // bf16 normalized s, frag layout (NPIX*128)

  hipMemsetAsync(ist, 0, (1024 + 512 + 512 + 8 + 8) * sizeof(float), stream);

  k_transpose_w<<<576, 256, 0, stream>>>(de_w, off_w, pw_w, wtb, wob, pwt);
  k_dw<<<BHWC / 256, 256, 0, stream>>>(x, dw_w, dw_b, h1);
  k_pw<<<NPIX / 32, 256, 0, stream>>>(h1, pwt, pw_b, s);
  k_instats<<<4 * 36, 256, 0, stream>>>(s, ist);
  k_infin<<<2, 256, 0, stream>>>(ist, ifm, ifr);
  k_norm<<<NPIX * 16 / 256, 256, 0, stream>>>(s, ifm, ifr, nsamp);
  k_offgemm<<<NPIX / 128, 256, 0, stream>>>(nsamp, wob, off_b, off);
  k_deform_f<<<NPIX / 64, 256, 0, stream>>>(nsamp, off, wtb, de_b, h1, gst);
  k_gnfin<<<1, 64, 0, stream>>>(gst, gfin);
  k_final<<<NPIX / 32, 256, 0, stream>>>(h1, s, ifm, ifr, gfin, gn_w, gn_b, out);
}

// Round 10
// 222.409 us; speedup vs baseline: 3.3006x; 1.0376x over previous
//
#include <hip/hip_runtime.h>
#include <hip/hip_bf16.h>
#include <math.h>

#define B_    4
#define C_    128
#define H_    96
#define W_    96
#define HW_   9216          // H*W
#define NPIX  36864         // B*HW
#define BHWC  4718592       // B*HW*C
#define BATCH_STRIDE 1179648 // HW*C

typedef __attribute__((ext_vector_type(8))) short bfrag8;
typedef __attribute__((ext_vector_type(4))) float f32x4;

static __device__ __forceinline__ short f2bf(float f) {
  __hip_bfloat16 h = __float2bfloat16(f);
  short s;
  __builtin_memcpy(&s, &h, 2);
  return s;
}
static __device__ __forceinline__ float bf2f(short s) {
  unsigned u = ((unsigned)(unsigned short)s) << 16;
  float f;
  __builtin_memcpy(&f, &u, 4);
  return f;
}

// ---------------- weight transposes ----------------
// wtb: bf16 A-frag order [k][mt(8)][kk(4)][lane(64)][j(8)] for de_w (147456)
// wob: bf16 A-frag order [k][mt(2)][kk(4)][lane(64)][j(8)] for off_w (36864)
// pwt: [c][oc] from pw_w [oc][c] (16384)
__global__ void k_transpose_w(const float* __restrict__ de_w,
                              const float* __restrict__ off_w,
                              const float* __restrict__ pw_w,
                              short* __restrict__ wtb, short* __restrict__ wob,
                              float* __restrict__ pwt) {
  int i = blockIdx.x * 256 + threadIdx.x;
  if (i < 147456) {
    int j  = i & 7;
    int l  = (i >> 3) & 63;
    int kk = (i >> 9) & 3;
    int mt = (i >> 11) & 7;
    int k  = i >> 14;
    int oc = mt * 16 + (l & 15);
    int c  = kk * 32 + ((l >> 4) << 3) + j;
    wtb[i] = f2bf(de_w[(oc * 128 + c) * 9 + k]);
  }
  if (i < 36864) {
    int j  = i & 7;
    int l  = (i >> 3) & 63;
    int kk = (i >> 9) & 3;
    int mt = (i >> 11) & 1;
    int k  = i >> 12;
    int oc = mt * 16 + (l & 15);
    int c  = kk * 32 + ((l >> 4) << 3) + j;
    wob[i] = (oc < 18) ? f2bf(off_w[(oc * 128 + c) * 9 + k]) : (short)0;
  }
  if (i < 16384) {
    int oc = i & 127; int c = i >> 7;
    pwt[i] = pw_w[oc * 128 + c];
  }
}

// ---------------- depthwise 3x3 + bias : NCHW in -> NCHW out ----------------
__global__ void k_dw(const float* __restrict__ x, const float* __restrict__ dw_w,
                     const float* __restrict__ dw_b, float* __restrict__ h1) {
  int i = blockIdx.x * 256 + threadIdx.x;
  if (i >= BHWC) return;
  int xx = i % 96; int yy = (i / 96) % 96; int c = (i / HW_) % 128; int b = i / BATCH_STRIDE;
  const float* xp = x + (b * 128 + c) * HW_;
  const float* wp = dw_w + c * 9;
  float acc = dw_b[c];
  #pragma unroll
  for (int dy = 0; dy < 3; ++dy) {
    int sy = yy + dy - 1;
    if (sy < 0 || sy >= 96) continue;
    #pragma unroll
    for (int dx = 0; dx < 3; ++dx) {
      int sx = xx + dx - 1;
      if (sx < 0 || sx >= 96) continue;
      acc += xp[sy * 96 + sx] * wp[dy * 3 + dx];
    }
  }
  h1[i] = acc;
}

// ---------------- pointwise 1x1 + bias : NCHW in -> BHWC out ----------------
__global__ __launch_bounds__(256) void k_pw(
    const float* __restrict__ h1, const float* __restrict__ pwt,
    const float* __restrict__ pw_b, float* __restrict__ s) {
  __shared__ float samp[32 * 128];
  int tid = threadIdx.x;
  int pixbase = blockIdx.x * 32;
  int b = pixbase / HW_;
  int hw0 = pixbase % HW_;

  if (tid < 128) {
    const float* hp = h1 + (size_t)(b * 128 + tid) * HW_ + hw0;
    #pragma unroll
    for (int p4 = 0; p4 < 8; ++p4) {
      float4 v = *(const float4*)(hp + p4 * 4);
      *(float4*)&samp[p4 * 512 + tid * 4] = v;
    }
  }
  __syncthreads();

  int to = tid & 31;
  int tp = tid >> 5;
  float acc[4][4];
  #pragma unroll
  for (int i = 0; i < 4; ++i)
    #pragma unroll
    for (int j = 0; j < 4; ++j) acc[i][j] = 0.f;

  const float4* wp4 = (const float4*)pwt;
  const float4* sp4 = (const float4*)&samp[tp * 512];
  #pragma unroll 8
  for (int c = 0; c < 128; ++c) {
    float4 w4 = wp4[c * 32 + to];
    float4 s4 = sp4[c];
    float wr[4] = {w4.x, w4.y, w4.z, w4.w};
    float sr[4] = {s4.x, s4.y, s4.z, s4.w};
    #pragma unroll
    for (int i = 0; i < 4; ++i)
      #pragma unroll
      for (int j = 0; j < 4; ++j)
        acc[i][j] = fmaf(wr[i], sr[j], acc[i][j]);
  }

  float b0 = pw_b[4 * to + 0], b1 = pw_b[4 * to + 1],
        b2 = pw_b[4 * to + 2], b3 = pw_b[4 * to + 3];
  #pragma unroll
  for (int j = 0; j < 4; ++j) {
    int pix = pixbase + 4 * tp + j;
    float4 v = make_float4(acc[0][j] + b0, acc[1][j] + b1, acc[2][j] + b2, acc[3][j] + b3);
    *(float4*)(s + (size_t)pix * 128 + 4 * to) = v;
  }
}

// ---------------- InstanceNorm stats (per b,c over HW) ----------------
__global__ void k_instats(const float* __restrict__ s, float* __restrict__ ist) {
  int b = blockIdx.x / 36; int tile = blockIdx.x % 36;
  int c = threadIdx.x & 127; int half = threadIdx.x >> 7;
  const float* base = s + (size_t)(b * HW_ + tile * 256) * 128;
  float sum = 0.f, sq = 0.f;
  for (int p = half; p < 256; p += 2) {
    float v = base[p * 128 + c];
    sum += v; sq += v * v;
  }
  __shared__ float r1[256], r2[256];
  r1[threadIdx.x] = sum; r2[threadIdx.x] = sq;
  __syncthreads();
  if (half == 0) {
    atomicAdd(&ist[(b * 128 + c) * 2],     r1[c] + r1[c + 128]);
    atomicAdd(&ist[(b * 128 + c) * 2 + 1], r2[c] + r2[c + 128]);
  }
}

__global__ void k_infin(const float* __restrict__ ist, float* __restrict__ ifm,
                        float* __restrict__ ifr) {
  int i = blockIdx.x * 256 + threadIdx.x;
  if (i >= 512) return;
  float mean = ist[2 * i] * (1.f / 9216.f);
  float var  = ist[2 * i + 1] * (1.f / 9216.f) - mean * mean;
  ifm[i] = mean;
  ifr[i] = rsqrtf(var + 1e-5f);
}

// ---------------- normalize s -> bf16 MFMA B-frag layout (global) ----------
__global__ __launch_bounds__(256) void k_norm(
    const float* __restrict__ s, const float* __restrict__ ifm,
    const float* __restrict__ ifr, short* __restrict__ nsamp) {
  int t = blockIdx.x * 256 + threadIdx.x;   // t < NPIX*16
  int lp = t & 15, g = (t >> 4) & 3, kk = (t >> 6) & 3, blk = t >> 8;
  int pix = blk * 16 + lp;
  int c0 = kk * 32 + g * 8;
  int b = pix / HW_;
  const float* sp = s + (size_t)pix * 128 + c0;
  float4 a0 = *(const float4*)sp, a1 = *(const float4*)(sp + 4);
  float4 m0 = *(const float4*)(ifm + b * 128 + c0), m1 = *(const float4*)(ifm + b * 128 + c0 + 4);
  float4 r0 = *(const float4*)(ifr + b * 128 + c0), r1 = *(const float4*)(ifr + b * 128 + c0 + 4);
  bfrag8 o;
  o[0] = f2bf(fmaxf((a0.x - m0.x) * r0.x, 0.f));
  o[1] = f2bf(fmaxf((a0.y - m0.y) * r0.y, 0.f));
  o[2] = f2bf(fmaxf((a0.z - m0.z) * r0.z, 0.f));
  o[3] = f2bf(fmaxf((a0.w - m0.w) * r0.w, 0.f));
  o[4] = f2bf(fmaxf((a1.x - m1.x) * r1.x, 0.f));
  o[5] = f2bf(fmaxf((a1.y - m1.y) * r1.y, 0.f));
  o[6] = f2bf(fmaxf((a1.z - m1.z) * r1.z, 0.f));
  o[7] = f2bf(fmaxf((a1.w - m1.w) * r1.w, 0.f));
  *(bfrag8*)(nsamp + (size_t)t * 8) = o;
}

// ---------------- offset conv as MFMA GEMM with shifted fragments ----------
__global__ __launch_bounds__(256) void k_offgemm(
    const short* __restrict__ nsamp, const short* __restrict__ wob,
    const float* __restrict__ off_b, float* __restrict__ off) {
  int tid = threadIdx.x;
  int lane = tid & 63, wv = tid >> 6;
  int p0 = blockIdx.x * 128 + wv * 32;
  int lp = lane & 15, g = lane >> 4;
  const bfrag8* np = (const bfrag8*)nsamp;
  const bfrag8* wp = (const bfrag8*)wob;

  f32x4 acc[2][2];
  #pragma unroll
  for (int m = 0; m < 2; ++m)
    #pragma unroll
    for (int n = 0; n < 2; ++n) acc[m][n] = (f32x4){0.f, 0.f, 0.f, 0.f};

  int pn0 = p0 + lp, pn1 = p0 + 16 + lp;
  int x0_ = pn0 % 96, y0_ = (pn0 % HW_) / 96;
  int x1_ = pn1 % 96, y1_ = (pn1 % HW_) / 96;
  const bfrag8 zf = {0, 0, 0, 0, 0, 0, 0, 0};

  for (int k = 0; k < 9; ++k) {
    int dy = k / 3 - 1, dx = k % 3 - 1;
    int sh = dy * 96 + dx;
    bool v0 = ((unsigned)(x0_ + dx) < 96u) && ((unsigned)(y0_ + dy) < 96u);
    bool v1 = ((unsigned)(x1_ + dx) < 96u) && ((unsigned)(y1_ + dy) < 96u);
    int q0 = min(max(pn0 + sh, 0), NPIX - 1);
    int q1 = min(max(pn1 + sh, 0), NPIX - 1);
    size_t a0 = (size_t)(q0 >> 4) * 256 + g * 16 + (q0 & 15);
    size_t a1 = (size_t)(q1 >> 4) * 256 + g * 16 + (q1 & 15);
    #pragma unroll
    for (int kk = 0; kk < 4; ++kk) {
      bfrag8 B0 = np[a0 + kk * 64]; B0 = v0 ? B0 : zf;
      bfrag8 B1 = np[a1 + kk * 64]; B1 = v1 ? B1 : zf;
      bfrag8 A0 = wp[((size_t)(k * 2 + 0) * 4 + kk) * 64 + lane];
      bfrag8 A1 = wp[((size_t)(k * 2 + 1) * 4 + kk) * 64 + lane];
      acc[0][0] = __builtin_amdgcn_mfma_f32_16x16x32_bf16(A0, B0, acc[0][0], 0, 0, 0);
      acc[0][1] = __builtin_amdgcn_mfma_f32_16x16x32_bf16(A0, B1, acc[0][1], 0, 0, 0);
      acc[1][0] = __builtin_amdgcn_mfma_f32_16x16x32_bf16(A1, B0, acc[1][0], 0, 0, 0);
      acc[1][1] = __builtin_amdgcn_mfma_f32_16x16x32_bf16(A1, B1, acc[1][1], 0, 0, 0);
    }
  }

  #pragma unroll
  for (int mt = 0; mt < 2; ++mt) {
    #pragma unroll
    for (int r = 0; r < 4; ++r) {
      int oc = mt * 16 + g * 4 + r;
      if (oc < 18) {
        float bb = off_b[oc];
        off[(size_t)oc * NPIX + p0 + lp]      = acc[mt][0][r] + bb;
        off[(size_t)oc * NPIX + p0 + 16 + lp] = acc[mt][1][r] + bb;
      }
    }
  }
}

// ---------------- fused deform: sample->LDS (dbuf) + MFMA + GN stats --------
// block = 64 pix x 128 oc, 4 waves; wave = 4 mt x 2 pixblk.
// XCD-aware bijective swizzle (576 = 8*72): each XCD gets 72 consecutive
// 64-pixel strips -> per-XCD gather working set ~1.2MB + wtb 288KB, L2-resident.
__global__ __launch_bounds__(256) void k_deform_f(
    const short* __restrict__ nsamp, const float* __restrict__ off,
    const short* __restrict__ wtb, const float* __restrict__ de_b,
    float* __restrict__ d, float* __restrict__ gst) {
  __shared__ short lbuf[2][4][4][64][8];   // [buf][pixblk][kk][lane][j], 32 KB
  __shared__ float r1[256], r2[256];
  int tid = threadIdx.x;
  int bid = blockIdx.x;
  int wg = (bid & 7) * 72 + (bid >> 3);    // XCD swizzle, bijective for 576
  int pixbase = wg * 64;

  // --- sampling mapping: 4 threads per pixel, 4 (kk, g=l4) slots each ---
  int pw_ = tid >> 2;            // pixel 0..63
  int l4  = tid & 3;             // g
  int pix_s = pixbase + pw_;
  int hw_s = pix_s % HW_;
  int ys = hw_s / 96, xs = hw_s % 96;
  int qb = (pix_s / HW_) * HW_;
  int pb_s = pw_ >> 4, lp_s = pw_ & 15;
  const bfrag8* np = (const bfrag8*)nsamp;

  // --- MFMA mapping ---
  int lane = tid & 63, wv = tid >> 6;
  int mtg0 = (wv & 1) * 4;
  int pb0 = (wv >> 1) * 2;
  const bfrag8* wp = (const bfrag8*)wtb;

  f32x4 acc[4][2];
  #pragma unroll
  for (int m = 0; m < 4; ++m)
    #pragma unroll
    for (int n = 0; n < 2; ++n) acc[m][n] = (f32x4){0.f, 0.f, 0.f, 0.f};

  auto SAMPLE = [&](int k, int buf) {
    float dy = off[(size_t)(2 * k)     * NPIX + pix_s];
    float dx = off[(size_t)(2 * k + 1) * NPIX + pix_s];
    float py = (float)ys + (float)(k / 3 - 1) + dy;
    float px = (float)xs + (float)(k % 3 - 1) + dx;
    float y0f = floorf(py), x0f = floorf(px);
    float ly = py - y0f, lx = px - x0f;
    int y0 = (int)y0f, x0 = (int)x0f;
    bool vy0 = (y0 >= 0) && (y0 < 96), vy1 = (y0 + 1 >= 0) && (y0 + 1 < 96);
    bool vx0 = (x0 >= 0) && (x0 < 96), vx1 = (x0 + 1 >= 0) && (x0 + 1 < 96);
    float w00 = (vy0 && vx0) ? (1.f - ly) * (1.f - lx) : 0.f;
    float w01 = (vy0 && vx1) ? (1.f - ly) * lx : 0.f;
    float w10 = (vy1 && vx0) ? ly * (1.f - lx) : 0.f;
    float w11 = (vy1 && vx1) ? ly * lx : 0.f;
    int yc0 = min(max(y0, 0), 95), yc1 = min(max(y0 + 1, 0), 95);
    int xc0 = min(max(x0, 0), 95), xc1 = min(max(x0 + 1, 0), 95);
    int q00 = qb + yc0 * 96 + xc0, q01 = qb + yc0 * 96 + xc1;
    int q10 = qb + yc1 * 96 + xc0, q11 = qb + yc1 * 96 + xc1;
    size_t b00 = (size_t)(q00 >> 4) * 256 + l4 * 16 + (q00 & 15);
    size_t b01 = (size_t)(q01 >> 4) * 256 + l4 * 16 + (q01 & 15);
    size_t b10 = (size_t)(q10 >> 4) * 256 + l4 * 16 + (q10 & 15);
    size_t b11 = (size_t)(q11 >> 4) * 256 + l4 * 16 + (q11 & 15);
    #pragma unroll
    for (int kk = 0; kk < 4; ++kk) {
      bfrag8 cA = np[b00 + kk * 64];
      bfrag8 cB = np[b01 + kk * 64];
      bfrag8 cC = np[b10 + kk * 64];
      bfrag8 cD = np[b11 + kk * 64];
      bfrag8 o;
      #pragma unroll
      for (int j = 0; j < 8; ++j) {
        float v = bf2f(cA[j]) * w00 + bf2f(cB[j]) * w01
                + bf2f(cC[j]) * w10 + bf2f(cD[j]) * w11;
        o[j] = f2bf(v);
      }
      *(bfrag8*)&lbuf[buf][pb_s][kk][l4 * 16 + lp_s][0] = o;
    }
  };

  SAMPLE(0, 0);
  __syncthreads();
  for (int k = 0; k < 9; ++k) {
    int cur = k & 1;
    if (k < 8) SAMPLE(k + 1, cur ^ 1);
    #pragma unroll
    for (int kk = 0; kk < 4; ++kk) {
      bfrag8 B0 = *(const bfrag8*)&lbuf[cur][pb0 + 0][kk][lane][0];
      bfrag8 B1 = *(const bfrag8*)&lbuf[cur][pb0 + 1][kk][lane][0];
      #pragma unroll
      for (int m = 0; m < 4; ++m) {
        bfrag8 af = wp[((size_t)((k * 8 + mtg0 + m) * 4 + kk)) * 64 + lane];
        acc[m][0] = __builtin_amdgcn_mfma_f32_16x16x32_bf16(af, B0, acc[m][0], 0, 0, 0);
        acc[m][1] = __builtin_amdgcn_mfma_f32_16x16x32_bf16(af, B1, acc[m][1], 0, 0, 0);
      }
    }
    __syncthreads();
  }

  // epilogue: bias + store + GN partials. D: lane l reg r -> oc_local=(l>>4)*4+r, pix=l&15
  int g = lane >> 4, lp = lane & 15;
  float lsum = 0.f, lsq = 0.f;
  #pragma unroll
  for (int m = 0; m < 4; ++m) {
    int oc = (mtg0 + m) * 16 + g * 4;
    float4 bias = *(const float4*)(de_b + oc);
    #pragma unroll
    for (int n = 0; n < 2; ++n) {
      int pix = pixbase + (pb0 + n) * 16 + lp;
      f32x4 a = acc[m][n];
      float4 v = make_float4(a[0] + bias.x, a[1] + bias.y, a[2] + bias.z, a[3] + bias.w);
      *(float4*)(d + (size_t)pix * 128 + oc) = v;
      lsum += v.x + v.y + v.z + v.w;
      lsq  += v.x * v.x + v.y * v.y + v.z * v.z + v.w * v.w;
    }
  }
  r1[tid] = lsum; r2[tid] = lsq;
  __syncthreads();
  for (int st = 128; st > 0; st >>= 1) {
    if (tid < st) { r1[tid] += r1[tid + st]; r2[tid] += r2[tid + st]; }
    __syncthreads();
  }
  if (tid == 0) {
    int b = pixbase / HW_;
    atomicAdd(&gst[b * 2],     r1[0]);
    atomicAdd(&gst[b * 2 + 1], r2[0]);
  }
}

__global__ void k_gnfin(const float* __restrict__ gst, float* __restrict__ gfin) {
  int b = threadIdx.x;
  if (b >= 4) return;
  const float invN = 1.f / (float)BATCH_STRIDE;
  float mean = gst[2 * b] * invN;
  float var  = gst[2 * b + 1] * invN - mean * mean;
  gfin[2 * b] = mean;
  gfin[2 * b + 1] = rsqrtf(var + 1e-5f);
}

// ---------------- final: GN + sigmoid gate + shortcut, LDS transpose --------
__global__ __launch_bounds__(256) void k_final(
    const float* __restrict__ d, const float* __restrict__ s,
    const float* __restrict__ ifm, const float* __restrict__ ifr,
    const float* __restrict__ gfin, const float* __restrict__ gn_w,
    const float* __restrict__ gn_b, float* __restrict__ out) {
  __shared__ float t[128 * 33];
  int tid = threadIdx.x;
  int pixbase = blockIdx.x * 32;
  int b = pixbase / HW_;
  int hw0 = pixbase % HW_;
  float gm = gfin[2 * b], gr = gfin[2 * b + 1];

  int px0 = tid >> 3;
  int c0  = (tid & 7) * 16;
  const float* dp = d + ((size_t)(pixbase + px0)) * 128;
  const float* sp = s + ((size_t)(pixbase + px0)) * 128;
  #pragma unroll
  for (int q = 0; q < 4; ++q) {
    int c = c0 + q * 4;
    float4 dv = *(const float4*)(dp + c);
    float4 sv = *(const float4*)(sp + c);
    float4 m4 = *(const float4*)(ifm + b * 128 + c);
    float4 r4 = *(const float4*)(ifr + b * 128 + c);
    float4 w4 = *(const float4*)(gn_w + c);
    float4 b4 = *(const float4*)(gn_b + c);
    float svn, dn, gg;
    svn = fmaxf((sv.x - m4.x) * r4.x, 0.f);
    dn  = (dv.x - gm) * gr * w4.x + b4.x;
    gg  = 1.f / (1.f + expf(-dn));
    t[(c + 0) * 33 + px0] = svn * (1.f + gg);
    svn = fmaxf((sv.y - m4.y) * r4.y, 0.f);
    dn  = (dv.y - gm) * gr * w4.y + b4.y;
    gg  = 1.f / (1.f + expf(-dn));
    t[(c + 1) * 33 + px0] = svn * (1.f + gg);
    svn = fmaxf((sv.z - m4.z) * r4.z, 0.f);
    dn  = (dv.z - gm) * gr * w4.z + b4.z;
    gg  = 1.f / (1.f + expf(-dn));
    t[(c + 2) * 33 + px0] = svn * (1.f + gg);
    svn = fmaxf((sv.w - m4.w) * r4.w, 0.f);
    dn  = (dv.w - gm) * gr * w4.w + b4.w;
    gg  = 1.f / (1.f + expf(-dn));
    t[(c + 3) * 33 + px0] = svn * (1.f + gg);
  }
  __syncthreads();
  if (tid < 128) {
    float* op = out + (size_t)(b * 128 + tid) * HW_ + hw0;
    #pragma unroll
    for (int p4 = 0; p4 < 8; ++p4) {
      float4 v = make_float4(t[tid * 33 + p4 * 4], t[tid * 33 + p4 * 4 + 1],
                             t[tid * 33 + p4 * 4 + 2], t[tid * 33 + p4 * 4 + 3]);
      *(float4*)(op + p4 * 4) = v;
    }
  }
}

extern "C" void kernel_launch(void* const* d_in, const int* in_sizes, int n_in,
                              void* d_out, int out_size, void* d_ws, size_t ws_size,
                              hipStream_t stream) {
  (void)in_sizes; (void)n_in; (void)out_size; (void)ws_size;
  const float* x     = (const float*)d_in[0];
  const float* dw_w  = (const float*)d_in[1];
  const float* dw_b  = (const float*)d_in[2];
  const float* pw_w  = (const float*)d_in[3];
  const float* pw_b  = (const float*)d_in[4];
  const float* off_w = (const float*)d_in[5];
  const float* off_b = (const float*)d_in[6];
  const float* de_w  = (const float*)d_in[7];
  const float* de_b  = (const float*)d_in[8];
  const float* gn_w  = (const float*)d_in[9];
  const float* gn_b  = (const float*)d_in[10];
  float* out = (float*)d_out;

  float* ws   = (float*)d_ws;
  float* h1   = ws;                 // NCHW depthwise out; reused as deform out d (BHWC)
  float* s    = h1 + BHWC;          // BHWC raw pw output (normalized on the fly)
  float* off  = s + BHWC;           // [18][NPIX] offsets (oc-major)
  short* wtb  = (short*)(off + NPIX * 18);  // bf16 A-frag de_w (147456 shorts)
  short* wob  = wtb + 147456;       // bf16 A-frag off_w (36864 shorts)
  float* pwt  = (float*)(wob + 36864);  // [c][oc] 16384
  float* ist  = pwt + 16384;        // [B][C][2] sum,sumsq
  float* ifm  = ist + 1024;         // [B][C] mean
  float* ifr  = ifm + 512;          // [B][C] rstd
  float* gst  = ifr + 512;          // [B][2]
  float* gfin = gst + 8;            // [B][2]
  short* nsamp = (short*)(gfin + 8);        // bf16 normalized s, frag layout (NPIX*128)

  hipMemsetAsync(ist, 0, (1024 + 512 + 512 + 8 + 8) * sizeof(float), stream);

  k_transpose_w<<<576, 256, 0, stream>>>(de_w, off_w, pw_w, wtb, wob, pwt);
  k_dw<<<BHWC / 256, 256, 0, stream>>>(x, dw_w, dw_b, h1);
  k_pw<<<NPIX / 32, 256, 0, stream>>>(h1, pwt, pw_b, s);
  k_instats<<<4 * 36, 256, 0, stream>>>(s, ist);
  k_infin<<<2, 256, 0, stream>>>(ist, ifm, ifr);
  k_norm<<<NPIX * 16 / 256, 256, 0, stream>>>(s, ifm, ifr, nsamp);
  k_offgemm<<<NPIX / 128, 256, 0, stream>>>(nsamp, wob, off_b, off);
  k_deform_f<<<NPIX / 64, 256, 0, stream>>>(nsamp, off, wtb, de_b, h1, gst);
  k_gnfin<<<1, 64, 0, stream>>>(gst, gfin);
  k_final<<<NPIX / 32, 256, 0, stream>>>(h1, s, ifm, ifr, gfin, gn_w, gn_b, out);
}